// Round 10
// baseline (925.179 us; speedup 1.0000x reference)
//
#include <hip/hip_runtime.h>
#include <stdint.h>

#define D 128
constexpr int NUc = 50000, NSc = 10000, NVc = 30000, Bc = 2048;
constexpr int N_US = 60000, N_UV = 80000, N_SV = 40000, N_ALL = 90000;
constexpr int BW = 64;       // bucket row width (shift 6)
constexpr int NBH = 1280;    // max buckets per graph (uv: 80000/64=1250)
constexpr int CHUNK = 4096;  // edges per scatter block
constexpr int CAPE = 6144;   // LDS staging capacity (edges)

typedef _Float16 h2v __attribute__((ext_vector_type(2)));
typedef _Float16 h4v __attribute__((ext_vector_type(4)));

// ---------------- Threefry-2x32 (JAX) ----------------
__host__ __device__ inline void threefry(uint32_t k0, uint32_t k1, uint32_t x0, uint32_t x1,
                                         uint32_t& o0, uint32_t& o1) {
  uint32_t ks2 = k0 ^ k1 ^ 0x1BD11BDAu;
  uint32_t v0 = x0 + k0, v1 = x1 + k1;
#define TFR(r) { v0 += v1; v1 = (v1 << (r)) | (v1 >> (32 - (r))); v1 ^= v0; }
  TFR(13) TFR(15) TFR(26) TFR(6)   v0 += k1;  v1 += ks2 + 1u;
  TFR(17) TFR(29) TFR(16) TFR(24)  v0 += ks2; v1 += k0 + 2u;
  TFR(13) TFR(15) TFR(26) TFR(6)   v0 += k0;  v1 += k1 + 3u;
  TFR(17) TFR(29) TFR(16) TFR(24)  v0 += k1;  v1 += ks2 + 4u;
  TFR(13) TFR(15) TFR(26) TFR(6)   v0 += ks2; v1 += k0 + 5u;
#undef TFR
  o0 = v0; o1 = v1;
}

__device__ __forceinline__ float unif01(uint32_t k0, uint32_t k1, uint32_t j) {
  uint32_t a, b;
  threefry(k0, k1, 0u, j, a, b);
  uint32_t bits = a ^ b;
  return __uint_as_float(0x3F800000u | (bits >> 9)) - 1.0f;
}

// ---------------- fused CSR build over 5 graphs ----------------
struct Bld {
  const int* rows[5]; const int* cols[5]; const float* vals[5];
  int* rp[5]; int* aux[5];
  int2* cv[5]; int2* ibuf[5];
  int* bhist;           // [totCBlk][NBH]
  int eBase[6];         // cumulative edges
  int sBlkBase[6];      // cumulative scan blocks
  int cBlkBase[6];      // cumulative chunk blocks
  int bktBase[6];       // cumulative buckets
  int nPlus1[5];
  int thrC[5], addC[5]; // col remap local->L0-global: c += (c>=thr ? add : 0)
};

// fused: per-chunk histogram (rp global atomics + LDS bucket hist -> bhist)
// + layer-0 fp16 table conversion in trailing blocks
__global__ __launch_bounds__(256) void k_histl0(Bld b, const float* __restrict__ u,
                                                const float* __restrict__ s,
                                                const float* __restrict__ v,
                                                _Float16* __restrict__ L0, int cBlkTot) {
  __shared__ int h[NBH];
  if ((int)blockIdx.x >= cBlkTot) {
    int gid = ((int)blockIdx.x - cBlkTot) * 256 + threadIdx.x;  // h4v units
    const int tot = N_ALL * (D / 4);
    if (gid >= tot) return;
    int r = gid >> 5, c4 = gid & 31;
    const float* src = (r < NUc) ? u + (size_t)r * D
                     : (r < NUc + NSc) ? s + (size_t)(r - NUc) * D
                                       : v + (size_t)(r - NUc - NSc) * D;
    float4 x = ((const float4*)src)[c4];
    ((h4v*)L0)[gid] = h4v{(_Float16)x.x, (_Float16)x.y, (_Float16)x.z, (_Float16)x.w};
    return;
  }
  int blk = blockIdx.x;
  int g = 0;
  while (blk >= b.cBlkBase[g + 1]) ++g;
  int lblk = blk - b.cBlkBase[g];
  int nbkt = b.bktBase[g + 1] - b.bktBase[g];
  int tid = threadIdx.x;
  for (int i = tid; i < nbkt; i += 256) h[i] = 0;
  __syncthreads();
  int nnzg = b.eBase[g + 1] - b.eBase[g];
  int e0 = lblk * CHUNK;
  int eEnd = min(e0 + CHUNK, nnzg);
  int* rp = b.rp[g];
  const int* rows = b.rows[g];
  for (int e = e0 + tid; e < eEnd; e += 256) {
    int row = __builtin_nontemporal_load(rows + e);
    atomicAdd(&rp[row + 1], 1);
    atomicAdd(&h[row >> 6], 1);
  }
  __syncthreads();
  int* outp = b.bhist + (size_t)blk * NBH;
  for (int i = tid; i < nbkt; i += 256) outp[i] = h[i];
}

__global__ __launch_bounds__(1024) void k_scan1f(Bld b) {
  __shared__ int wsum[16];
  int blk = blockIdx.x;
  int g = 0;
  while (blk >= b.sBlkBase[g + 1]) ++g;
  int lb = blk - b.sBlkBase[g];
  int n = b.nPlus1[g];
  int* data = b.rp[g];
  int tid = threadIdx.x, lane = tid & 63, w = tid >> 6;
  int i = lb * 1024 + tid;
  int x = (i < n) ? data[i] : 0;
  for (int off = 1; off < 64; off <<= 1) {
    int t = __shfl_up(x, off, 64);
    if (lane >= off) x += t;
  }
  if (lane == 63) wsum[w] = x;
  __syncthreads();
  if (w == 0 && lane < 16) {
    int s = wsum[lane];
    for (int off = 1; off < 16; off <<= 1) {
      int t = __shfl_up(s, off, 64);
      if (lane >= off) s += t;
    }
    wsum[lane] = s;
  }
  __syncthreads();
  int woff = (w > 0) ? wsum[w - 1] : 0;
  if (i < n) data[i] = x + woff;
  if (tid == 1023) b.aux[g][lb] = x + woff;
}

__global__ void k_scan2f(Bld b) {
  int g = blockIdx.x;
  int nb = b.sBlkBase[g + 1] - b.sBlkBase[g];
  int* aux = b.aux[g];
  int lane = threadIdx.x;  // 64 threads
  int carry = 0;
  for (int base = 0; base < nb; base += 64) {
    int i = base + lane;
    int v = (i < nb) ? aux[i] : 0;
    for (int off = 1; off < 64; off <<= 1) {
      int t = __shfl_up(v, off, 64);
      if (lane >= off) v += t;
    }
    if (i < nb) aux[i] = v + carry;
    carry += __shfl(v, 63, 64);
  }
}

__global__ __launch_bounds__(1024) void k_scan3f(Bld b) {
  int blk = blockIdx.x;
  int g = 0;
  while (blk >= b.sBlkBase[g + 1]) ++g;
  int lb = blk - b.sBlkBase[g];
  if (lb == 0) return;
  int i = lb * 1024 + threadIdx.x;
  if (i < b.nPlus1[g]) b.rp[g][i] += b.aux[g][lb - 1];
}

// one wave per bucket: scan per-block counts -> exclusive global bases
__global__ void k_bscan(Bld b) {
  int gid = blockIdx.x * blockDim.x + threadIdx.x;
  int w = gid >> 6, lane = gid & 63;
  if (w >= b.bktBase[5]) return;
  int g = 0;
  while (w >= b.bktBase[g + 1]) ++g;
  int lb = w - b.bktBase[g];
  int carry = b.rp[g][lb * BW];  // bucket start in graph-local CSR space
  int blk0 = b.cBlkBase[g], nblk = b.cBlkBase[g + 1] - blk0;
  for (int t = 0; t < nblk; t += 64) {
    int i = t + lane;
    int v = (i < nblk) ? b.bhist[(size_t)(blk0 + i) * NBH + lb] : 0;
    int x = v;
    for (int off = 1; off < 64; off <<= 1) {
      int tt = __shfl_up(x, off, 64);
      if (lane >= off) x += tt;
    }
    if (i < nblk) b.bhist[(size_t)(blk0 + i) * NBH + lb] = x - v + carry;
    carry += __shfl(x, 63, 64);
  }
}

// deterministic bucket scatter (LDS cursors, no global atomics)
// emits {global_col | rowlow<<17, val as duplicated f16x2}
__global__ __launch_bounds__(256) void k_bscat(Bld b) {
  __shared__ int cur[NBH];
  int blk = blockIdx.x;
  int g = 0;
  while (blk >= b.cBlkBase[g + 1]) ++g;
  int lblk = blk - b.cBlkBase[g];
  int nbkt = b.bktBase[g + 1] - b.bktBase[g];
  int tid = threadIdx.x;
  const int* bh = b.bhist + (size_t)blk * NBH;
  for (int i = tid; i < nbkt; i += 256) cur[i] = bh[i];
  __syncthreads();
  int nnzg = b.eBase[g + 1] - b.eBase[g];
  int e0 = lblk * CHUNK;
  int eEnd = min(e0 + CHUNK, nnzg);
  int2* ib = b.ibuf[g];
  int thr = b.thrC[g], add = b.addC[g];
  const int* rows = b.rows[g];
  const int* cols = b.cols[g];
  const float* vals = b.vals[g];
  for (int e = e0 + tid; e < eEnd; e += 256) {
    int row = __builtin_nontemporal_load(rows + e);
    int c = __builtin_nontemporal_load(cols + e);
    float v = __builtin_nontemporal_load(vals + e);
    c += (c >= thr) ? add : 0;
    uint32_t hb = (uint32_t)__builtin_bit_cast(unsigned short, (_Float16)v);
    int pos = atomicAdd(&cur[row >> 6], 1);
    ib[pos] = make_int2(c | ((row & (BW - 1)) << 17), (int)(hb | (hb << 16)));
  }
}

// level-2: within-bucket row ordering via LDS cursors + coalesced stream-out
__global__ __launch_bounds__(256) void k_scatl2(Bld b) {
  __shared__ int lcur[BW];
  __shared__ int2 stg[CAPE];
  int bid = blockIdx.x;
  int g = 0;
  while (bid >= b.bktBase[g + 1]) ++g;
  int lb = bid - b.bktBase[g];
  int n = b.nPlus1[g] - 1;
  int r0 = lb * BW;
  int rowsInB = min(BW, n - r0);
  const int* rp = b.rp[g];
  int segStart = rp[r0];
  int segLen = rp[r0 + rowsInB] - segStart;
  int tid = threadIdx.x;
  if (tid < rowsInB) lcur[tid] = rp[r0 + tid] - segStart;
  __syncthreads();
  const int2* ib = b.ibuf[g];
  int2* cv = b.cv[g];
  for (int i = tid; i < segLen; i += 256) {
    unsigned long long raw =
        __builtin_nontemporal_load((const unsigned long long*)(ib + segStart + i));
    int vx = (int)(uint32_t)raw;
    int vy = (int)(uint32_t)(raw >> 32);
    int rowlow = ((uint32_t)vx) >> 17;
    int2 outv = make_int2(vx & 0x1FFFF, vy);
    int lpos = atomicAdd(&lcur[rowlow], 1);
    if (lpos < CAPE) stg[lpos] = outv;
    else cv[segStart + lpos] = outv;
  }
  __syncthreads();
  int lim = min(segLen, CAPE);
  for (int i = tid; i < lim; i += 256) cv[segStart + i] = stg[i];
}

// ---------------- gather core: 2 edges/wave, h4v loads, packed-f16 FMA ----------------
// lanes 0-31 handle edge k, lanes 32-63 edge k+1; each lane loads 8B (4 cols).
// cv loads are non-temporal (single-use stream; keep table in cache instead).
__device__ __forceinline__ void gather_row(const int* __restrict__ rp,
                                           const int2* __restrict__ cv,
                                           const char* __restrict__ spc, int rl, int lane,
                                           float& fx, float& fy) {
  int s = rp[rl], e = rp[rl + 1];
  int half = lane >> 5;
  uint32_t lcol = (uint32_t)(lane & 31) << 3;  // byte offset within 256B row
  h4v a0 = {0, 0, 0, 0}, a1 = {0, 0, 0, 0};
  int k = s;
  for (; k + 3 < e; k += 4) {
    unsigned long long r0 =
        __builtin_nontemporal_load((const unsigned long long*)(cv + k + half));
    unsigned long long r1 =
        __builtin_nontemporal_load((const unsigned long long*)(cv + k + 2 + half));
    uint32_t c0 = (uint32_t)r0, c1 = (uint32_t)r1;
    uint32_t v0 = (uint32_t)(r0 >> 32), v1 = (uint32_t)(r1 >> 32);
    h4v x0 = *(const h4v*)(spc + (c0 << 8) + lcol);
    h4v x1 = *(const h4v*)(spc + (c1 << 8) + lcol);
    uint2 d0 = {v0, v0};
    uint2 d1 = {v1, v1};
    a0 += x0 * __builtin_bit_cast(h4v, d0);
    a1 += x1 * __builtin_bit_cast(h4v, d1);
  }
  for (; k < e; k += 2) {
    int ke = k + half;
    int idx = (ke < e) ? ke : (e - 1);
    unsigned long long r0 =
        __builtin_nontemporal_load((const unsigned long long*)(cv + idx));
    uint32_t cc = (uint32_t)r0;
    uint32_t vv = (ke < e) ? (uint32_t)(r0 >> 32) : 0u;
    h4v x = *(const h4v*)(spc + (cc << 8) + lcol);
    uint2 dd = {vv, vv};
    a0 += x * __builtin_bit_cast(h4v, dd);
  }
  float f0 = (float)a0.x + (float)a1.x;
  float f1 = (float)a0.y + (float)a1.y;
  float f2 = (float)a0.z + (float)a1.z;
  float f3 = (float)a0.w + (float)a1.w;
  f0 += __shfl_xor(f0, 32, 64);
  f1 += __shfl_xor(f1, 32, 64);
  f2 += __shfl_xor(f2, 32, 64);
  f3 += __shfl_xor(f3, 32, 64);
  int srcl = lane >> 1;  // lane srcl holds cols [4*(srcl&31) .. +4)
  float v0 = __shfl(f0, srcl, 64);
  float v1 = __shfl(f1, srcl, 64);
  float v2 = __shfl(f2, srcl, 64);
  float v3 = __shfl(f3, srcl, 64);
  fx = (lane & 1) ? v2 : v0;
  fy = (lane & 1) ? v3 : v1;
}

// ---------------- fused propagate layer over 3 graphs ----------------
struct GP {
  const int* rp[3]; const int2* cv[3];
  const char* src[3];        // gather source (pre-offset to global-col space)
  const _Float16* accIn[3];  // indexed by gr
  _Float16* accOut[3];       // indexed by rl
  _Float16* dst[3];          // indexed by gr (pre-offset); null on layer 2
  uint32_t k0[3], k1[3];
  int rowThr[3], rowAdd[3];  // gr = rl + (rl>=thr ? add : 0)
  int rBase[4];
  float div;
};

__global__ void k_gprop3(GP p) {
  int gid = blockIdx.x * blockDim.x + threadIdx.x;
  int r = gid >> 6, lane = gid & 63;
  if (r >= p.rBase[3]) return;
  int g = 0;
  while (r >= p.rBase[g + 1]) ++g;
  int rl = r - p.rBase[g];
  float fx, fy;
  gather_row(p.rp[g], p.cv[g], p.src[g], rl, lane, fx, fy);
  uint32_t j0 = (uint32_t)rl * D + (uint32_t)lane * 2;
  float u0 = unif01(p.k0[g], p.k1[g], j0);
  float u1 = unif01(p.k0[g], p.k1[g], j0 + 1u);
  float s2 = u0 * u0 + u1 * u1;
  for (int m = 1; m < 64; m <<= 1) s2 += __shfl_xor(s2, m, 64);
  float nn = fmaxf(sqrtf(s2), 1e-12f);
  float sg0 = (fx > 0.f) ? 1.f : ((fx < 0.f) ? -1.f : 0.f);
  float sg1 = (fy > 0.f) ? 1.f : ((fy < 0.f) ? -1.f : 0.f);
  float nf0 = fx + sg0 * (u0 / nn) * 0.1f;
  float nf1 = fy + sg1 * (u1 / nn) * 0.1f;
  float fs = nf0 * nf0 + nf1 * nf1;
  for (int m = 1; m < 64; m <<= 1) fs += __shfl_xor(fs, m, 64);
  float fn = fmaxf(sqrtf(fs), 1e-12f);
  int gr = rl + ((rl >= p.rowThr[g]) ? p.rowAdd[g] : 0);
  h2v ai = ((const h2v*)p.accIn[g])[(size_t)gr * (D / 2) + lane];
  float ax = ((float)ai.x + nf0 / fn) / p.div;
  float ay = ((float)ai.y + nf1 / fn) / p.div;
  ((h2v*)p.accOut[g])[(size_t)rl * (D / 2) + lane] = h2v{(_Float16)ax, (_Float16)ay};
  if (p.dst[g])
    ((h2v*)p.dst[g])[(size_t)gr * (D / 2) + lane] = h2v{(_Float16)nf0, (_Float16)nf1};
}

// ---------------- fused aggregate over 2 graphs ----------------
struct GA {
  const int* rp[2]; const int2* cv[2];
  const char* src[2]; _Float16* dst[2];
  uint32_t k0[2], k1[2];
  int rBase[3];
};

__global__ void k_gagg2(GA a) {
  int gid = blockIdx.x * blockDim.x + threadIdx.x;
  int r = gid >> 6, lane = gid & 63;
  if (r >= a.rBase[2]) return;
  int g = (r >= a.rBase[1]) ? 1 : 0;
  int rl = r - a.rBase[g];
  float fx, fy;
  gather_row(a.rp[g], a.cv[g], a.src[g], rl, lane, fx, fy);
  uint32_t j0 = (uint32_t)rl * D + (uint32_t)lane * 2;
  float u0 = unif01(a.k0[g], a.k1[g], j0);
  float u1 = unif01(a.k0[g], a.k1[g], j0 + 1u);
  float s2 = u0 * u0 + u1 * u1;
  for (int m = 1; m < 64; m <<= 1) s2 += __shfl_xor(s2, m, 64);
  float nn = fmaxf(sqrtf(s2), 1e-12f);
  float sg0 = (fx > 0.f) ? 1.f : ((fx < 0.f) ? -1.f : 0.f);
  float sg1 = (fy > 0.f) ? 1.f : ((fy < 0.f) ? -1.f : 0.f);
  ((h2v*)a.dst[g])[(size_t)rl * (D / 2) + lane] =
      h2v{(_Float16)(fx + sg0 * (u0 / nn) * 0.1f), (_Float16)(fy + sg1 * (u1 / nn) * 0.1f)};
}

// ---------------- MGA attention (fp16 in/out, in-place into e0buf) ----------------
__global__ void k_mga(_Float16* __restrict__ e0buf, const _Float16* __restrict__ UVa,
                      const _Float16* __restrict__ UVs, const _Float16* __restrict__ SVu,
                      const _Float16* __restrict__ SVa, const float* __restrict__ w,
                      const float* __restrict__ bptr) {
  int gid = blockIdx.x * blockDim.x + threadIdx.x;
  int wave = gid >> 6, lane = gid & 63;
  int n = NUc + NSc;
  if (wave >= n) return;
  const _Float16* e1 = (wave < NUc) ? UVa + (size_t)wave * D : UVs + (size_t)(wave - NUc) * D;
  const _Float16* e2 = (wave < NUc) ? SVu + (size_t)wave * D : SVa + (size_t)(wave - NUc) * D;
  _Float16* e0 = e0buf + (size_t)wave * D;
  int c = lane * 2;
  h2v h0 = *(const h2v*)(e0 + c), h1 = *(const h2v*)(e1 + c), h2_ = *(const h2v*)(e2 + c);
  float2 v0 = {(float)h0.x, (float)h0.y};
  float2 v1 = {(float)h1.x, (float)h1.y};
  float2 v2 = {(float)h2_.x, (float)h2_.y};
  float2 wl = *(const float2*)(w + c);
  float2 wh = *(const float2*)(w + D + c);
  float d00 = v0.x * wl.x + v0.y * wl.y;
  float c0 = v0.x * wh.x + v0.y * wh.y;
  float c1 = v1.x * wh.x + v1.y * wh.y;
  float c2 = v2.x * wh.x + v2.y * wh.y;
  for (int m = 1; m < 64; m <<= 1) {
    d00 += __shfl_xor(d00, m, 64);
    c0 += __shfl_xor(c0, m, 64);
    c1 += __shfl_xor(c1, m, 64);
    c2 += __shfl_xor(c2, m, 64);
  }
  float b = bptr[0];
  float l0 = d00 + c0 + b, l1 = d00 + c1 + b, l2v = d00 + c2 + b;
  float mx = fmaxf(l0, fmaxf(l1, l2v));
  float a0 = expf(l0 - mx), a1 = expf(l1 - mx), a2 = expf(l2v - mx);
  float s = a0 + a1 + a2;
  a0 /= s; a1 /= s; a2 /= s;
  float ox = a0 * v0.x + a1 * v1.x + a2 * v2.x;
  float oy = a0 * v0.y + a1 * v1.y + a2 * v2.y;
  *(h2v*)(e0 + c) = h2v{(_Float16)ox, (_Float16)oy};
}

// ---------------- batch gather: BPR + normalized P rows ----------------
__global__ void k_batch(const _Float16* __restrict__ reps, const int* __restrict__ users,
                        const int* __restrict__ streamers, float* __restrict__ Pu,
                        float* __restrict__ Ps, float* __restrict__ accs) {
  int gid = blockIdx.x * blockDim.x + threadIdx.x;
  int wave = gid >> 6, lane = gid & 63;
  if (wave >= Bc) return;
  int u = users[wave];
  int s0 = streamers[wave * 2], s1 = streamers[wave * 2 + 1];
  h2v uh = ((const h2v*)(reps + (size_t)u * D))[lane];
  h2v ah = ((const h2v*)(reps + (size_t)(NUc + s0) * D))[lane];
  h2v ch = ((const h2v*)(reps + (size_t)(NUc + s1) * D))[lane];
  float2 uv = {(float)uh.x, (float)uh.y};
  float2 av = {(float)ah.x, (float)ah.y};
  float2 cv = {(float)ch.x, (float)ch.y};
  float p0 = uv.x * av.x + uv.y * av.y;
  float p1 = uv.x * cv.x + uv.y * cv.y;
  float un = uv.x * uv.x + uv.y * uv.y;
  float an = av.x * av.x + av.y * av.y;
  for (int m = 1; m < 64; m <<= 1) {
    p0 += __shfl_xor(p0, m, 64);
    p1 += __shfl_xor(p1, m, 64);
    un += __shfl_xor(un, m, 64);
    an += __shfl_xor(an, m, 64);
  }
  if (lane == 0) {
    float t = p0 - p1;
    float term = fmaxf(-t, 0.f) + log1pf(expf(-fabsf(t)));  // -log_sigmoid(t)
    atomicAdd(&accs[0], term);
  }
  float und = fmaxf(sqrtf(un), 1e-12f);
  float andv = fmaxf(sqrtf(an), 1e-12f);
  ((float2*)(Pu + (size_t)wave * D))[lane] = float2{uv.x / und, uv.y / und};
  ((float2*)(Ps + (size_t)wave * D))[lane] = float2{av.x / andv, av.y / andv};
}

// ---------------- contrastive GEMM: S[b] += sum_j exp(5*dot) ----------------
__global__ __launch_bounds__(256) void k_cgemm(const float* __restrict__ Pu,
                                               const float* __restrict__ Ps,
                                               float* __restrict__ Su,
                                               float* __restrict__ Ss) {
  const float* P = blockIdx.z ? Ps : Pu;
  float* S = blockIdx.z ? Ss : Su;
  __shared__ float A[32][132];
  __shared__ float BT[128][68];
  int tid = threadIdx.x;
  int tx = tid & 15, ty = tid >> 4;
  int brow0 = blockIdx.x * 32;
  int j0 = blockIdx.y * 512;
#pragma unroll
  for (int i = 0; i < 4; ++i) {
    int idx = tid + i * 256;
    int r = idx >> 5, c4 = idx & 31;
    float4 v = ((const float4*)(P + (size_t)(brow0 + r) * D))[c4];
    *(float4*)&A[r][c4 * 4] = v;
  }
  float s[2] = {0.f, 0.f};
  for (int jt = 0; jt < 8; ++jt) {
    __syncthreads();
#pragma unroll
    for (int i = 0; i < 8; ++i) {
      int idx = tid + i * 256;
      int r = idx >> 5, c4 = idx & 31;
      float4 v = ((const float4*)(P + (size_t)(j0 + jt * 64 + r) * D))[c4];
      BT[c4 * 4 + 0][r] = v.x;
      BT[c4 * 4 + 1][r] = v.y;
      BT[c4 * 4 + 2][r] = v.z;
      BT[c4 * 4 + 3][r] = v.w;
    }
    __syncthreads();
    float acc[2][4] = {};
    for (int k = 0; k < 128; k += 4) {
      float4 a0 = *(const float4*)&A[ty * 2 + 0][k];
      float4 a1 = *(const float4*)&A[ty * 2 + 1][k];
      float4 b0 = *(const float4*)&BT[k + 0][tx * 4];
      float4 b1 = *(const float4*)&BT[k + 1][tx * 4];
      float4 b2 = *(const float4*)&BT[k + 2][tx * 4];
      float4 b3 = *(const float4*)&BT[k + 3][tx * 4];
      acc[0][0] = fmaf(a0.x, b0.x, acc[0][0]); acc[0][1] = fmaf(a0.x, b0.y, acc[0][1]);
      acc[0][2] = fmaf(a0.x, b0.z, acc[0][2]); acc[0][3] = fmaf(a0.x, b0.w, acc[0][3]);
      acc[1][0] = fmaf(a1.x, b0.x, acc[1][0]); acc[1][1] = fmaf(a1.x, b0.y, acc[1][1]);
      acc[1][2] = fmaf(a1.x, b0.z, acc[1][2]); acc[1][3] = fmaf(a1.x, b0.w, acc[1][3]);
      acc[0][0] = fmaf(a0.y, b1.x, acc[0][0]); acc[0][1] = fmaf(a0.y, b1.y, acc[0][1]);
      acc[0][2] = fmaf(a0.y, b1.z, acc[0][2]); acc[0][3] = fmaf(a0.y, b1.w, acc[0][3]);
      acc[1][0] = fmaf(a1.y, b1.x, acc[1][0]); acc[1][1] = fmaf(a1.y, b1.y, acc[1][1]);
      acc[1][2] = fmaf(a1.y, b1.z, acc[1][2]); acc[1][3] = fmaf(a1.y, b1.w, acc[1][3]);
      acc[0][0] = fmaf(a0.z, b2.x, acc[0][0]); acc[0][1] = fmaf(a0.z, b2.y, acc[0][1]);
      acc[0][2] = fmaf(a0.z, b2.z, acc[0][2]); acc[0][3] = fmaf(a0.z, b2.w, acc[0][3]);
      acc[1][0] = fmaf(a1.z, b2.x, acc[1][0]); acc[1][1] = fmaf(a1.z, b2.y, acc[1][1]);
      acc[1][2] = fmaf(a1.z, b2.z, acc[1][2]); acc[1][3] = fmaf(a1.z, b2.w, acc[1][3]);
      acc[0][0] = fmaf(a0.w, b3.x, acc[0][0]); acc[0][1] = fmaf(a0.w, b3.y, acc[0][1]);
      acc[0][2] = fmaf(a0.w, b3.z, acc[0][2]); acc[0][3] = fmaf(a0.w, b3.w, acc[0][3]);
      acc[1][0] = fmaf(a1.w, b3.x, acc[1][0]); acc[1][1] = fmaf(a1.w, b3.y, acc[1][1]);
      acc[1][2] = fmaf(a1.w, b3.z, acc[1][2]); acc[1][3] = fmaf(a1.w, b3.w, acc[1][3]);
    }
#pragma unroll
    for (int i = 0; i < 2; ++i)
#pragma unroll
      for (int jj = 0; jj < 4; ++jj) s[i] += __expf(5.0f * acc[i][jj]);
  }
#pragma unroll
  for (int i = 0; i < 2; ++i) {
    for (int off = 1; off < 16; off <<= 1) s[i] += __shfl_xor(s[i], off, 64);
    if (tx == 0) atomicAdd(&S[brow0 + ty * 2 + i], s[i]);
  }
}

__global__ void k_cfinal(const float* __restrict__ Pu, const float* __restrict__ Ps,
                         const float* __restrict__ Su, const float* __restrict__ Ss,
                         float* __restrict__ accs) {
  int gid = blockIdx.x * blockDim.x + threadIdx.x;
  int wave = gid >> 6, lane = gid & 63;
  if (wave >= 2 * Bc) return;
  int loss = wave >> 11, b = wave & (Bc - 1);
  const float* P = loss ? Ps : Pu;
  const float* S = loss ? Ss : Su;
  float2 p = ((const float2*)(P + (size_t)b * D))[lane];
  float pos = p.x * p.x + p.y * p.y;
  for (int m = 1; m < 64; m <<= 1) pos += __shfl_xor(pos, m, 64);
  if (lane == 0) atomicAdd(&accs[1 + loss], logf(S[b]) - 5.0f * pos);
}

__global__ void k_final(const float* __restrict__ accs, float* __restrict__ out) {
  if (threadIdx.x == 0 && blockIdx.x == 0) {
    out[0] = accs[0] / (float)Bc;
    out[1] = 0.5f * (accs[1] + accs[2]) / (float)Bc;
  }
}

// ---------------- launch ----------------
extern "C" void kernel_launch(void* const* d_in, const int* in_sizes, int n_in,
                              void* d_out, int out_size, void* d_ws, size_t ws_size,
                              hipStream_t stream) {
  const float* usersF = (const float*)d_in[0];
  const float* streamersF = (const float*)d_in[1];
  const float* videosF = (const float*)d_in[2];
  const float* linW = (const float*)d_in[3];
  const float* linB = (const float*)d_in[4];
  const int* grows[5] = {(const int*)d_in[5], (const int*)d_in[8], (const int*)d_in[11],
                         (const int*)d_in[14], (const int*)d_in[17]};
  const int* gcols[5] = {(const int*)d_in[6], (const int*)d_in[9], (const int*)d_in[12],
                         (const int*)d_in[15], (const int*)d_in[18]};
  const float* gvals[5] = {(const float*)d_in[7], (const float*)d_in[10], (const float*)d_in[13],
                           (const float*)d_in[16], (const float*)d_in[19]};
  const int* users = (const int*)d_in[20];
  const int* streamers = (const int*)d_in[21];
  int nnz[5] = {in_sizes[5], in_sizes[8], in_sizes[11], in_sizes[14], in_sizes[17]};
  int gn[5] = {N_US, N_UV, N_SV, NUc, NSc};  // us, uv, sv, uva, sva
  float* out = (float*)d_out;

  // ---------- workspace ----------
  char* pb = (char*)d_ws;
  auto allocH = [&](size_t nh) { _Float16* p = (_Float16*)pb; pb += nh * 2; return p; };
  _Float16* L0 = allocH((size_t)N_ALL * D);
  // layer-1 outputs in GLOBAL row space: us 60000 rows (identity),
  // uv 90000 rows (hole at [50000,60000)), sv 40000 rows (global - 50000)
  _Float16* Th0 = allocH((size_t)N_US * D);
  _Float16* Th1 = allocH((size_t)N_ALL * D);
  _Float16* Th2 = allocH((size_t)N_SV * D);
  _Float16* Ac[3] = {allocH((size_t)N_US * D), allocH((size_t)N_UV * D), allocH((size_t)N_SV * D)};
  _Float16* UVsH = allocH((size_t)NSc * D);
  _Float16* SVuH = allocH((size_t)NUc * D);
  pb = (char*)(((uintptr_t)pb + 15) & ~(uintptr_t)15);
  float* Pu = (float*)pb; pb += (size_t)Bc * D * 4;
  float* Ps = (float*)pb; pb += (size_t)Bc * D * 4;
  float* accs = (float*)pb; pb += 16 * 4;
  float* Su = (float*)pb; pb += Bc * 4;
  float* Ss = (float*)pb; pb += Bc * 4;
  int totE = nnz[0] + nnz[1] + nnz[2] + nnz[3] + nnz[4];
  int2* cvAll = (int2*)pb; pb += (size_t)totE * 8;
  int2* ibAll = (int2*)pb; pb += (size_t)totE * 8;
  int* rpAll = (int*)pb;
  int totRP = 0;
  for (int g = 0; g < 5; ++g) totRP += gn[g] + 1;
  pb += (size_t)totRP * 4;
  int* auxAll = (int*)pb; pb += 5 * 128 * 4;

  // ---------- CSR build descriptor ----------
  Bld b;
  int totCBlk = 0;
  {
    int eA = 0, sA = 0, rpO = 0, cvO = 0, bA = 0, cA = 0;
    // col remap local -> L0 global: c += (c>=thr ? add : 0)
    int thrC[5] = {0x7fffffff, NUc, 0, 0x7fffffff, 0x7fffffff};
    int addC[5] = {0, NSc, NUc, 0, 0};
    for (int g = 0; g < 5; ++g) {
      b.rows[g] = grows[g]; b.cols[g] = gcols[g]; b.vals[g] = gvals[g];
      b.thrC[g] = thrC[g]; b.addC[g] = addC[g];
      b.eBase[g] = eA; eA += nnz[g];
      int n1 = gn[g] + 1;
      b.nPlus1[g] = n1;
      b.sBlkBase[g] = sA; sA += (n1 + 1023) / 1024;
      b.cBlkBase[g] = cA; cA += (nnz[g] + CHUNK - 1) / CHUNK;
      b.rp[g] = rpAll + rpO; rpO += n1;
      b.aux[g] = auxAll + g * 128;
      b.cv[g] = cvAll + cvO;
      b.ibuf[g] = ibAll + cvO; cvO += nnz[g];
      b.bktBase[g] = bA; bA += (gn[g] + BW - 1) / BW;
    }
    b.eBase[5] = eA;
    b.sBlkBase[5] = sA;
    b.cBlkBase[5] = cA;
    b.bktBase[5] = bA;
    totCBlk = cA;
  }
  int totBlk = b.sBlkBase[5];
  int totBkt = b.bktBase[5];
  int* bhistAll = (int*)pb; pb += (size_t)totCBlk * NBH * 4;
  b.bhist = bhistAll;

  // ---------- keys (JAX threefry, partitionable fold-in split) ----------
  uint32_t kus[2], kuv[2], ksv[2], kauv[2], kasv[2];
  threefry(0u, 42u, 0u, 0u, kus[0], kus[1]);
  threefry(0u, 42u, 0u, 1u, kuv[0], kuv[1]);
  threefry(0u, 42u, 0u, 2u, ksv[0], ksv[1]);
  threefry(0u, 42u, 0u, 3u, kauv[0], kauv[1]);
  threefry(0u, 42u, 0u, 4u, kasv[0], kasv[1]);
  uint32_t kusL[2][2], kuvL[2][2], ksvL[2][2];
  for (uint32_t i = 0; i < 2; ++i) {
    threefry(kus[0], kus[1], 0u, i, kusL[i][0], kusL[i][1]);
    threefry(kuv[0], kuv[1], 0u, i, kuvL[i][0], kuvL[i][1]);
    threefry(ksv[0], ksv[1], 0u, i, ksvL[i][0], ksvL[i][1]);
  }

  // ---------- CSR build (deterministic two-level scatter) + L0 table ----------
  hipMemsetAsync(rpAll, 0, (size_t)totRP * sizeof(int), stream);
  int l0Blocks = (N_ALL * (D / 4) + 255) / 256;
  k_histl0<<<(unsigned)(totCBlk + l0Blocks), 256, 0, stream>>>(b, usersF, streamersF, videosF,
                                                               L0, totCBlk);
  k_scan1f<<<(unsigned)totBlk, 1024, 0, stream>>>(b);
  k_scan2f<<<5, 64, 0, stream>>>(b);
  k_scan3f<<<(unsigned)totBlk, 1024, 0, stream>>>(b);
  k_bscan<<<(unsigned)(((size_t)totBkt * 64 + 255) / 256), 256, 0, stream>>>(b);
  k_bscat<<<(unsigned)totCBlk, 256, 0, stream>>>(b);
  k_scatl2<<<(unsigned)totBkt, 256, 0, stream>>>(b);

  // ---------- propagate layers (fused over us/uv/sv) ----------
  GP p1, p2;
  const uint32_t* kL1[3] = {kusL[0], kuvL[0], ksvL[0]};
  const uint32_t* kL2[3] = {kusL[1], kuvL[1], ksvL[1]};
  int rB[4] = {0, N_US, N_US + N_UV, N_US + N_UV + N_SV};
  // per-graph row remap rl -> global row gr
  int rThr[3] = {0x7fffffff, NUc, 0};
  int rAdd[3] = {0, NSc, NUc};
  // dst pointers pre-offset so dst[gr] is correct
  _Float16* dstP[3] = {Th0, Th1, Th2 - (size_t)NUc * D};
  // layer-2 gather sources pre-offset so src[(gcol<<8)] is correct
  const char* src2[3] = {(const char*)Th0, (const char*)Th1,
                         (const char*)Th2 - (size_t)NUc * D * 2};
  for (int g = 0; g < 3; ++g) {
    p1.rp[g] = b.rp[g]; p1.cv[g] = b.cv[g];
    p1.src[g] = (const char*)L0; p1.accIn[g] = L0; p1.accOut[g] = Ac[g]; p1.dst[g] = dstP[g];
    p1.k0[g] = kL1[g][0]; p1.k1[g] = kL1[g][1];
    p1.rowThr[g] = rThr[g]; p1.rowAdd[g] = rAdd[g];
    p1.rBase[g] = rB[g];
    p2.rp[g] = b.rp[g]; p2.cv[g] = b.cv[g];
    p2.src[g] = src2[g]; p2.accIn[g] = Ac[g]; p2.accOut[g] = Ac[g]; p2.dst[g] = nullptr;
    p2.k0[g] = kL2[g][0]; p2.k1[g] = kL2[g][1];
    p2.rowThr[g] = 0x7fffffff; p2.rowAdd[g] = 0;
    p2.rBase[g] = rB[g];
  }
  p1.rBase[3] = rB[3]; p2.rBase[3] = rB[3];
  p1.div = 1.0f; p2.div = 3.0f;
  unsigned gpropBlocks = (unsigned)(((size_t)rB[3] * 64 + 255) / 256);
  k_gprop3<<<gpropBlocks, 256, 0, stream>>>(p1);
  k_gprop3<<<gpropBlocks, 256, 0, stream>>>(p2);

  // ---------- aggregates (fused) ----------
  GA ga;
  ga.rp[0] = b.rp[3]; ga.cv[0] = b.cv[3];
  ga.src[0] = (const char*)(Ac[2] + (size_t)NSc * D);  // SV video part (cols 0..NV)
  ga.dst[0] = SVuH; ga.k0[0] = kauv[0]; ga.k1[0] = kauv[1];
  ga.rp[1] = b.rp[4]; ga.cv[1] = b.cv[4];
  ga.src[1] = (const char*)(Ac[1] + (size_t)NUc * D);  // UV video part
  ga.dst[1] = UVsH; ga.k0[1] = kasv[0]; ga.k1[1] = kasv[1];
  ga.rBase[0] = 0; ga.rBase[1] = NUc; ga.rBase[2] = NUc + NSc;
  k_gagg2<<<(unsigned)(((size_t)(NUc + NSc) * 64 + 255) / 256), 256, 0, stream>>>(ga);

  // ---------- attention + losses ----------
  k_mga<<<(unsigned)((NUc + NSc + 3) / 4), 256, 0, stream>>>(Ac[0], Ac[1], UVsH, SVuH, Ac[2],
                                                             linW, linB);
  hipMemsetAsync(accs, 0, (size_t)(16 + 2 * Bc) * sizeof(float), stream);
  k_batch<<<(unsigned)((Bc + 3) / 4), 256, 0, stream>>>(Ac[0], users, streamers, Pu, Ps, accs);
  k_cgemm<<<dim3(Bc / 32, 4, 2), 256, 0, stream>>>(Pu, Ps, Su, Ss);
  k_cfinal<<<(unsigned)((2 * Bc + 3) / 4), 256, 0, stream>>>(Pu, Ps, Su, Ss, accs);
  k_final<<<1, 64, 0, stream>>>(accs, out);
}

// Round 11
// 865.897 us; speedup vs baseline: 1.0685x; 1.0685x over previous
//
#include <hip/hip_runtime.h>
#include <stdint.h>

#define D 128
constexpr int NUc = 50000, NSc = 10000, NVc = 30000, Bc = 2048;
constexpr int N_US = 60000, N_UV = 80000, N_SV = 40000, N_ALL = 90000;
constexpr int BW = 64;       // bucket row width (shift 6)
constexpr int NBH = 1280;    // max buckets per graph (uv: 80000/64=1250)
constexpr int CHUNK = 4096;  // edges per scatter block
constexpr int CAPE = 6144;   // LDS staging capacity (edges)

typedef _Float16 h2v __attribute__((ext_vector_type(2)));
typedef _Float16 h4v __attribute__((ext_vector_type(4)));

// ---------------- Threefry-2x32 (JAX) ----------------
__host__ __device__ inline void threefry(uint32_t k0, uint32_t k1, uint32_t x0, uint32_t x1,
                                         uint32_t& o0, uint32_t& o1) {
  uint32_t ks2 = k0 ^ k1 ^ 0x1BD11BDAu;
  uint32_t v0 = x0 + k0, v1 = x1 + k1;
#define TFR(r) { v0 += v1; v1 = (v1 << (r)) | (v1 >> (32 - (r))); v1 ^= v0; }
  TFR(13) TFR(15) TFR(26) TFR(6)   v0 += k1;  v1 += ks2 + 1u;
  TFR(17) TFR(29) TFR(16) TFR(24)  v0 += ks2; v1 += k0 + 2u;
  TFR(13) TFR(15) TFR(26) TFR(6)   v0 += k0;  v1 += k1 + 3u;
  TFR(17) TFR(29) TFR(16) TFR(24)  v0 += k1;  v1 += ks2 + 4u;
  TFR(13) TFR(15) TFR(26) TFR(6)   v0 += ks2; v1 += k0 + 5u;
#undef TFR
  o0 = v0; o1 = v1;
}

__device__ __forceinline__ float unif01(uint32_t k0, uint32_t k1, uint32_t j) {
  uint32_t a, b;
  threefry(k0, k1, 0u, j, a, b);
  uint32_t bits = a ^ b;
  return __uint_as_float(0x3F800000u | (bits >> 9)) - 1.0f;
}

// ---------------- fused CSR build over 5 graphs ----------------
struct Bld {
  const int* rows[5]; const int* cols[5]; const float* vals[5];
  int* rp[5]; int* aux[5];
  int2* cv[5]; int2* ibuf[5];
  int* bhist;           // [totCBlk][NBH]
  int eBase[6];         // cumulative edges
  int sBlkBase[6];      // cumulative scan blocks
  int cBlkBase[6];      // cumulative chunk blocks
  int bktBase[6];       // cumulative buckets
  int nPlus1[5];
  int thrC[5], addC[5]; // col remap local->L0-global: c += (c>=thr ? add : 0)
};

// fused: per-chunk histogram (rp global atomics + LDS bucket hist -> bhist)
// + layer-0 fp16 table conversion in trailing blocks
__global__ __launch_bounds__(256) void k_histl0(Bld b, const float* __restrict__ u,
                                                const float* __restrict__ s,
                                                const float* __restrict__ v,
                                                _Float16* __restrict__ L0, int cBlkTot) {
  __shared__ int h[NBH];
  if ((int)blockIdx.x >= cBlkTot) {
    int gid = ((int)blockIdx.x - cBlkTot) * 256 + threadIdx.x;  // h4v units
    const int tot = N_ALL * (D / 4);
    if (gid >= tot) return;
    int r = gid >> 5, c4 = gid & 31;
    const float* src = (r < NUc) ? u + (size_t)r * D
                     : (r < NUc + NSc) ? s + (size_t)(r - NUc) * D
                                       : v + (size_t)(r - NUc - NSc) * D;
    float4 x = ((const float4*)src)[c4];
    ((h4v*)L0)[gid] = h4v{(_Float16)x.x, (_Float16)x.y, (_Float16)x.z, (_Float16)x.w};
    return;
  }
  int blk = blockIdx.x;
  int g = 0;
  while (blk >= b.cBlkBase[g + 1]) ++g;
  int lblk = blk - b.cBlkBase[g];
  int nbkt = b.bktBase[g + 1] - b.bktBase[g];
  int tid = threadIdx.x;
  for (int i = tid; i < nbkt; i += 256) h[i] = 0;
  __syncthreads();
  int nnzg = b.eBase[g + 1] - b.eBase[g];
  int e0 = lblk * CHUNK;
  int eEnd = min(e0 + CHUNK, nnzg);
  int* rp = b.rp[g];
  const int* rows = b.rows[g];
  for (int e = e0 + tid; e < eEnd; e += 256) {
    int row = __builtin_nontemporal_load(rows + e);
    atomicAdd(&rp[row + 1], 1);
    atomicAdd(&h[row >> 6], 1);
  }
  __syncthreads();
  int* outp = b.bhist + (size_t)blk * NBH;
  for (int i = tid; i < nbkt; i += 256) outp[i] = h[i];
}

__global__ __launch_bounds__(1024) void k_scan1f(Bld b) {
  __shared__ int wsum[16];
  int blk = blockIdx.x;
  int g = 0;
  while (blk >= b.sBlkBase[g + 1]) ++g;
  int lb = blk - b.sBlkBase[g];
  int n = b.nPlus1[g];
  int* data = b.rp[g];
  int tid = threadIdx.x, lane = tid & 63, w = tid >> 6;
  int i = lb * 1024 + tid;
  int x = (i < n) ? data[i] : 0;
  for (int off = 1; off < 64; off <<= 1) {
    int t = __shfl_up(x, off, 64);
    if (lane >= off) x += t;
  }
  if (lane == 63) wsum[w] = x;
  __syncthreads();
  if (w == 0 && lane < 16) {
    int s = wsum[lane];
    for (int off = 1; off < 16; off <<= 1) {
      int t = __shfl_up(s, off, 64);
      if (lane >= off) s += t;
    }
    wsum[lane] = s;
  }
  __syncthreads();
  int woff = (w > 0) ? wsum[w - 1] : 0;
  if (i < n) data[i] = x + woff;
  if (tid == 1023) b.aux[g][lb] = x + woff;
}

__global__ void k_scan2f(Bld b) {
  int g = blockIdx.x;
  int nb = b.sBlkBase[g + 1] - b.sBlkBase[g];
  int* aux = b.aux[g];
  int lane = threadIdx.x;  // 64 threads
  int carry = 0;
  for (int base = 0; base < nb; base += 64) {
    int i = base + lane;
    int v = (i < nb) ? aux[i] : 0;
    for (int off = 1; off < 64; off <<= 1) {
      int t = __shfl_up(v, off, 64);
      if (lane >= off) v += t;
    }
    if (i < nb) aux[i] = v + carry;
    carry += __shfl(v, 63, 64);
  }
}

__global__ __launch_bounds__(1024) void k_scan3f(Bld b) {
  int blk = blockIdx.x;
  int g = 0;
  while (blk >= b.sBlkBase[g + 1]) ++g;
  int lb = blk - b.sBlkBase[g];
  if (lb == 0) return;
  int i = lb * 1024 + threadIdx.x;
  if (i < b.nPlus1[g]) b.rp[g][i] += b.aux[g][lb - 1];
}

// one wave per bucket: scan per-block counts -> exclusive global bases
__global__ void k_bscan(Bld b) {
  int gid = blockIdx.x * blockDim.x + threadIdx.x;
  int w = gid >> 6, lane = gid & 63;
  if (w >= b.bktBase[5]) return;
  int g = 0;
  while (w >= b.bktBase[g + 1]) ++g;
  int lb = w - b.bktBase[g];
  int carry = b.rp[g][lb * BW];  // bucket start in graph-local CSR space
  int blk0 = b.cBlkBase[g], nblk = b.cBlkBase[g + 1] - blk0;
  for (int t = 0; t < nblk; t += 64) {
    int i = t + lane;
    int v = (i < nblk) ? b.bhist[(size_t)(blk0 + i) * NBH + lb] : 0;
    int x = v;
    for (int off = 1; off < 64; off <<= 1) {
      int tt = __shfl_up(x, off, 64);
      if (lane >= off) x += tt;
    }
    if (i < nblk) b.bhist[(size_t)(blk0 + i) * NBH + lb] = x - v + carry;
    carry += __shfl(x, 63, 64);
  }
}

// deterministic bucket scatter (LDS cursors, no global atomics)
// emits {global_col | rowlow<<17, val as duplicated f16x2}
__global__ __launch_bounds__(256) void k_bscat(Bld b) {
  __shared__ int cur[NBH];
  int blk = blockIdx.x;
  int g = 0;
  while (blk >= b.cBlkBase[g + 1]) ++g;
  int lblk = blk - b.cBlkBase[g];
  int nbkt = b.bktBase[g + 1] - b.bktBase[g];
  int tid = threadIdx.x;
  const int* bh = b.bhist + (size_t)blk * NBH;
  for (int i = tid; i < nbkt; i += 256) cur[i] = bh[i];
  __syncthreads();
  int nnzg = b.eBase[g + 1] - b.eBase[g];
  int e0 = lblk * CHUNK;
  int eEnd = min(e0 + CHUNK, nnzg);
  int2* ib = b.ibuf[g];
  int thr = b.thrC[g], add = b.addC[g];
  const int* rows = b.rows[g];
  const int* cols = b.cols[g];
  const float* vals = b.vals[g];
  for (int e = e0 + tid; e < eEnd; e += 256) {
    int row = __builtin_nontemporal_load(rows + e);
    int c = __builtin_nontemporal_load(cols + e);
    float v = __builtin_nontemporal_load(vals + e);
    c += (c >= thr) ? add : 0;
    uint32_t hb = (uint32_t)__builtin_bit_cast(unsigned short, (_Float16)v);
    int pos = atomicAdd(&cur[row >> 6], 1);
    ib[pos] = make_int2(c | ((row & (BW - 1)) << 17), (int)(hb | (hb << 16)));
  }
}

// level-2: within-bucket row ordering via LDS cursors + coalesced stream-out
__global__ __launch_bounds__(256) void k_scatl2(Bld b) {
  __shared__ int lcur[BW];
  __shared__ int2 stg[CAPE];
  int bid = blockIdx.x;
  int g = 0;
  while (bid >= b.bktBase[g + 1]) ++g;
  int lb = bid - b.bktBase[g];
  int n = b.nPlus1[g] - 1;
  int r0 = lb * BW;
  int rowsInB = min(BW, n - r0);
  const int* rp = b.rp[g];
  int segStart = rp[r0];
  int segLen = rp[r0 + rowsInB] - segStart;
  int tid = threadIdx.x;
  if (tid < rowsInB) lcur[tid] = rp[r0 + tid] - segStart;
  __syncthreads();
  const int2* ib = b.ibuf[g];
  int2* cv = b.cv[g];
  for (int i = tid; i < segLen; i += 256) {
    unsigned long long raw =
        __builtin_nontemporal_load((const unsigned long long*)(ib + segStart + i));
    int vx = (int)(uint32_t)raw;
    int vy = (int)(uint32_t)(raw >> 32);
    int rowlow = ((uint32_t)vx) >> 17;
    int2 outv = make_int2(vx & 0x1FFFF, vy);
    int lpos = atomicAdd(&lcur[rowlow], 1);
    if (lpos < CAPE) stg[lpos] = outv;
    else cv[segStart + lpos] = outv;
  }
  __syncthreads();
  int lim = min(segLen, CAPE);
  for (int i = tid; i < lim; i += 256) cv[segStart + i] = stg[i];
}

// ---------------- gather core: 2 edges/wave, h4v loads, packed-f16 FMA ----------------
// lanes 0-31 handle edge k, lanes 32-63 edge k+1; each lane loads 8B (4 cols).
// cv loads are REGULAR (line reused across iterations — NT hurt, round 10).
__device__ __forceinline__ void gather_row(const int* __restrict__ rp,
                                           const int2* __restrict__ cv,
                                           const char* __restrict__ spc, int rl, int lane,
                                           float& fx, float& fy) {
  int s = rp[rl], e = rp[rl + 1];
  int half = lane >> 5;
  uint32_t lcol = (uint32_t)(lane & 31) << 3;  // byte offset within 256B row
  h4v a0 = {0, 0, 0, 0}, a1 = {0, 0, 0, 0};
  int k = s;
  for (; k + 3 < e; k += 4) {
    int2 q0 = cv[k + half];
    int2 q1 = cv[k + 2 + half];
    h4v x0 = *(const h4v*)(spc + ((uint32_t)q0.x << 8) + lcol);
    h4v x1 = *(const h4v*)(spc + ((uint32_t)q1.x << 8) + lcol);
    uint2 d0 = {(uint32_t)q0.y, (uint32_t)q0.y};
    uint2 d1 = {(uint32_t)q1.y, (uint32_t)q1.y};
    a0 += x0 * __builtin_bit_cast(h4v, d0);
    a1 += x1 * __builtin_bit_cast(h4v, d1);
  }
  for (; k < e; k += 2) {
    int ke = k + half;
    int idx = (ke < e) ? ke : (e - 1);
    int2 q = cv[idx];
    uint32_t vv = (ke < e) ? (uint32_t)q.y : 0u;
    h4v x = *(const h4v*)(spc + ((uint32_t)q.x << 8) + lcol);
    uint2 dd = {vv, vv};
    a0 += x * __builtin_bit_cast(h4v, dd);
  }
  float f0 = (float)a0.x + (float)a1.x;
  float f1 = (float)a0.y + (float)a1.y;
  float f2 = (float)a0.z + (float)a1.z;
  float f3 = (float)a0.w + (float)a1.w;
  f0 += __shfl_xor(f0, 32, 64);
  f1 += __shfl_xor(f1, 32, 64);
  f2 += __shfl_xor(f2, 32, 64);
  f3 += __shfl_xor(f3, 32, 64);
  int srcl = lane >> 1;  // lane srcl holds cols [4*(srcl&31) .. +4)
  float v0 = __shfl(f0, srcl, 64);
  float v1 = __shfl(f1, srcl, 64);
  float v2 = __shfl(f2, srcl, 64);
  float v3 = __shfl(f3, srcl, 64);
  fx = (lane & 1) ? v2 : v0;
  fy = (lane & 1) ? v3 : v1;
}

// ---------------- fused propagate layer over 3 graphs ----------------
struct GP {
  const int* rp[3]; const int2* cv[3];
  const char* src[3];        // gather source (pre-offset to global-col space)
  const _Float16* accIn[3];  // indexed by gr
  _Float16* accOut[3];       // indexed by rl
  _Float16* dst[3];          // indexed by gr (pre-offset); null on layer 2
  uint32_t k0[3], k1[3];
  int rowThr[3], rowAdd[3];  // gr = rl + (rl>=thr ? add : 0)
  int rBase[4];
  float div;
};

__global__ void k_gprop3(GP p) {
  int gid = blockIdx.x * blockDim.x + threadIdx.x;
  int r = gid >> 6, lane = gid & 63;
  if (r >= p.rBase[3]) return;
  int g = 0;
  while (r >= p.rBase[g + 1]) ++g;
  int rl = r - p.rBase[g];
  float fx, fy;
  gather_row(p.rp[g], p.cv[g], p.src[g], rl, lane, fx, fy);
  uint32_t j0 = (uint32_t)rl * D + (uint32_t)lane * 2;
  float u0 = unif01(p.k0[g], p.k1[g], j0);
  float u1 = unif01(p.k0[g], p.k1[g], j0 + 1u);
  float s2 = u0 * u0 + u1 * u1;
  for (int m = 1; m < 64; m <<= 1) s2 += __shfl_xor(s2, m, 64);
  float nn = fmaxf(sqrtf(s2), 1e-12f);
  float sg0 = (fx > 0.f) ? 1.f : ((fx < 0.f) ? -1.f : 0.f);
  float sg1 = (fy > 0.f) ? 1.f : ((fy < 0.f) ? -1.f : 0.f);
  float nf0 = fx + sg0 * (u0 / nn) * 0.1f;
  float nf1 = fy + sg1 * (u1 / nn) * 0.1f;
  float fs = nf0 * nf0 + nf1 * nf1;
  for (int m = 1; m < 64; m <<= 1) fs += __shfl_xor(fs, m, 64);
  float fn = fmaxf(sqrtf(fs), 1e-12f);
  int gr = rl + ((rl >= p.rowThr[g]) ? p.rowAdd[g] : 0);
  h2v ai = ((const h2v*)p.accIn[g])[(size_t)gr * (D / 2) + lane];
  float ax = ((float)ai.x + nf0 / fn) / p.div;
  float ay = ((float)ai.y + nf1 / fn) / p.div;
  ((h2v*)p.accOut[g])[(size_t)rl * (D / 2) + lane] = h2v{(_Float16)ax, (_Float16)ay};
  if (p.dst[g])
    ((h2v*)p.dst[g])[(size_t)gr * (D / 2) + lane] = h2v{(_Float16)nf0, (_Float16)nf1};
}

// ---------------- fused aggregate over 2 graphs ----------------
struct GA {
  const int* rp[2]; const int2* cv[2];
  const char* src[2]; _Float16* dst[2];
  uint32_t k0[2], k1[2];
  int rBase[3];
};

__global__ void k_gagg2(GA a) {
  int gid = blockIdx.x * blockDim.x + threadIdx.x;
  int r = gid >> 6, lane = gid & 63;
  if (r >= a.rBase[2]) return;
  int g = (r >= a.rBase[1]) ? 1 : 0;
  int rl = r - a.rBase[g];
  float fx, fy;
  gather_row(a.rp[g], a.cv[g], a.src[g], rl, lane, fx, fy);
  uint32_t j0 = (uint32_t)rl * D + (uint32_t)lane * 2;
  float u0 = unif01(a.k0[g], a.k1[g], j0);
  float u1 = unif01(a.k0[g], a.k1[g], j0 + 1u);
  float s2 = u0 * u0 + u1 * u1;
  for (int m = 1; m < 64; m <<= 1) s2 += __shfl_xor(s2, m, 64);
  float nn = fmaxf(sqrtf(s2), 1e-12f);
  float sg0 = (fx > 0.f) ? 1.f : ((fx < 0.f) ? -1.f : 0.f);
  float sg1 = (fy > 0.f) ? 1.f : ((fy < 0.f) ? -1.f : 0.f);
  ((h2v*)a.dst[g])[(size_t)rl * (D / 2) + lane] =
      h2v{(_Float16)(fx + sg0 * (u0 / nn) * 0.1f), (_Float16)(fy + sg1 * (u1 / nn) * 0.1f)};
}

// ---------------- MGA attention (fp16 in/out, in-place into e0buf) ----------------
__global__ void k_mga(_Float16* __restrict__ e0buf, const _Float16* __restrict__ UVa,
                      const _Float16* __restrict__ UVs, const _Float16* __restrict__ SVu,
                      const _Float16* __restrict__ SVa, const float* __restrict__ w,
                      const float* __restrict__ bptr) {
  int gid = blockIdx.x * blockDim.x + threadIdx.x;
  int wave = gid >> 6, lane = gid & 63;
  int n = NUc + NSc;
  if (wave >= n) return;
  const _Float16* e1 = (wave < NUc) ? UVa + (size_t)wave * D : UVs + (size_t)(wave - NUc) * D;
  const _Float16* e2 = (wave < NUc) ? SVu + (size_t)wave * D : SVa + (size_t)(wave - NUc) * D;
  _Float16* e0 = e0buf + (size_t)wave * D;
  int c = lane * 2;
  h2v h0 = *(const h2v*)(e0 + c), h1 = *(const h2v*)(e1 + c), h2_ = *(const h2v*)(e2 + c);
  float2 v0 = {(float)h0.x, (float)h0.y};
  float2 v1 = {(float)h1.x, (float)h1.y};
  float2 v2 = {(float)h2_.x, (float)h2_.y};
  float2 wl = *(const float2*)(w + c);
  float2 wh = *(const float2*)(w + D + c);
  float d00 = v0.x * wl.x + v0.y * wl.y;
  float c0 = v0.x * wh.x + v0.y * wh.y;
  float c1 = v1.x * wh.x + v1.y * wh.y;
  float c2 = v2.x * wh.x + v2.y * wh.y;
  for (int m = 1; m < 64; m <<= 1) {
    d00 += __shfl_xor(d00, m, 64);
    c0 += __shfl_xor(c0, m, 64);
    c1 += __shfl_xor(c1, m, 64);
    c2 += __shfl_xor(c2, m, 64);
  }
  float b = bptr[0];
  float l0 = d00 + c0 + b, l1 = d00 + c1 + b, l2v = d00 + c2 + b;
  float mx = fmaxf(l0, fmaxf(l1, l2v));
  float a0 = expf(l0 - mx), a1 = expf(l1 - mx), a2 = expf(l2v - mx);
  float s = a0 + a1 + a2;
  a0 /= s; a1 /= s; a2 /= s;
  float ox = a0 * v0.x + a1 * v1.x + a2 * v2.x;
  float oy = a0 * v0.y + a1 * v1.y + a2 * v2.y;
  *(h2v*)(e0 + c) = h2v{(_Float16)ox, (_Float16)oy};
}

// ---------------- batch gather: BPR + normalized P rows ----------------
__global__ void k_batch(const _Float16* __restrict__ reps, const int* __restrict__ users,
                        const int* __restrict__ streamers, float* __restrict__ Pu,
                        float* __restrict__ Ps, float* __restrict__ accs) {
  int gid = blockIdx.x * blockDim.x + threadIdx.x;
  int wave = gid >> 6, lane = gid & 63;
  if (wave >= Bc) return;
  int u = users[wave];
  int s0 = streamers[wave * 2], s1 = streamers[wave * 2 + 1];
  h2v uh = ((const h2v*)(reps + (size_t)u * D))[lane];
  h2v ah = ((const h2v*)(reps + (size_t)(NUc + s0) * D))[lane];
  h2v ch = ((const h2v*)(reps + (size_t)(NUc + s1) * D))[lane];
  float2 uv = {(float)uh.x, (float)uh.y};
  float2 av = {(float)ah.x, (float)ah.y};
  float2 cv = {(float)ch.x, (float)ch.y};
  float p0 = uv.x * av.x + uv.y * av.y;
  float p1 = uv.x * cv.x + uv.y * cv.y;
  float un = uv.x * uv.x + uv.y * uv.y;
  float an = av.x * av.x + av.y * av.y;
  for (int m = 1; m < 64; m <<= 1) {
    p0 += __shfl_xor(p0, m, 64);
    p1 += __shfl_xor(p1, m, 64);
    un += __shfl_xor(un, m, 64);
    an += __shfl_xor(an, m, 64);
  }
  if (lane == 0) {
    float t = p0 - p1;
    float term = fmaxf(-t, 0.f) + log1pf(expf(-fabsf(t)));  // -log_sigmoid(t)
    atomicAdd(&accs[0], term);
  }
  float und = fmaxf(sqrtf(un), 1e-12f);
  float andv = fmaxf(sqrtf(an), 1e-12f);
  ((float2*)(Pu + (size_t)wave * D))[lane] = float2{uv.x / und, uv.y / und};
  ((float2*)(Ps + (size_t)wave * D))[lane] = float2{av.x / andv, av.y / andv};
}

// ---------------- contrastive GEMM: S[b] += sum_j exp(5*dot) ----------------
__global__ __launch_bounds__(256) void k_cgemm(const float* __restrict__ Pu,
                                               const float* __restrict__ Ps,
                                               float* __restrict__ Su,
                                               float* __restrict__ Ss) {
  const float* P = blockIdx.z ? Ps : Pu;
  float* S = blockIdx.z ? Ss : Su;
  __shared__ float A[32][132];
  __shared__ float BT[128][68];
  int tid = threadIdx.x;
  int tx = tid & 15, ty = tid >> 4;
  int brow0 = blockIdx.x * 32;
  int j0 = blockIdx.y * 512;
#pragma unroll
  for (int i = 0; i < 4; ++i) {
    int idx = tid + i * 256;
    int r = idx >> 5, c4 = idx & 31;
    float4 v = ((const float4*)(P + (size_t)(brow0 + r) * D))[c4];
    *(float4*)&A[r][c4 * 4] = v;
  }
  float s[2] = {0.f, 0.f};
  for (int jt = 0; jt < 8; ++jt) {
    __syncthreads();
#pragma unroll
    for (int i = 0; i < 8; ++i) {
      int idx = tid + i * 256;
      int r = idx >> 5, c4 = idx & 31;
      float4 v = ((const float4*)(P + (size_t)(j0 + jt * 64 + r) * D))[c4];
      BT[c4 * 4 + 0][r] = v.x;
      BT[c4 * 4 + 1][r] = v.y;
      BT[c4 * 4 + 2][r] = v.z;
      BT[c4 * 4 + 3][r] = v.w;
    }
    __syncthreads();
    float acc[2][4] = {};
    for (int k = 0; k < 128; k += 4) {
      float4 a0 = *(const float4*)&A[ty * 2 + 0][k];
      float4 a1 = *(const float4*)&A[ty * 2 + 1][k];
      float4 b0 = *(const float4*)&BT[k + 0][tx * 4];
      float4 b1 = *(const float4*)&BT[k + 1][tx * 4];
      float4 b2 = *(const float4*)&BT[k + 2][tx * 4];
      float4 b3 = *(const float4*)&BT[k + 3][tx * 4];
      acc[0][0] = fmaf(a0.x, b0.x, acc[0][0]); acc[0][1] = fmaf(a0.x, b0.y, acc[0][1]);
      acc[0][2] = fmaf(a0.x, b0.z, acc[0][2]); acc[0][3] = fmaf(a0.x, b0.w, acc[0][3]);
      acc[1][0] = fmaf(a1.x, b0.x, acc[1][0]); acc[1][1] = fmaf(a1.x, b0.y, acc[1][1]);
      acc[1][2] = fmaf(a1.x, b0.z, acc[1][2]); acc[1][3] = fmaf(a1.x, b0.w, acc[1][3]);
      acc[0][0] = fmaf(a0.y, b1.x, acc[0][0]); acc[0][1] = fmaf(a0.y, b1.y, acc[0][1]);
      acc[0][2] = fmaf(a0.y, b1.z, acc[0][2]); acc[0][3] = fmaf(a0.y, b1.w, acc[0][3]);
      acc[1][0] = fmaf(a1.y, b1.x, acc[1][0]); acc[1][1] = fmaf(a1.y, b1.y, acc[1][1]);
      acc[1][2] = fmaf(a1.y, b1.z, acc[1][2]); acc[1][3] = fmaf(a1.y, b1.w, acc[1][3]);
      acc[0][0] = fmaf(a0.z, b2.x, acc[0][0]); acc[0][1] = fmaf(a0.z, b2.y, acc[0][1]);
      acc[0][2] = fmaf(a0.z, b2.z, acc[0][2]); acc[0][3] = fmaf(a0.z, b2.w, acc[0][3]);
      acc[1][0] = fmaf(a1.z, b2.x, acc[1][0]); acc[1][1] = fmaf(a1.z, b2.y, acc[1][1]);
      acc[1][2] = fmaf(a1.z, b2.z, acc[1][2]); acc[1][3] = fmaf(a1.z, b2.w, acc[1][3]);
      acc[0][0] = fmaf(a0.w, b3.x, acc[0][0]); acc[0][1] = fmaf(a0.w, b3.y, acc[0][1]);
      acc[0][2] = fmaf(a0.w, b3.z, acc[0][2]); acc[0][3] = fmaf(a0.w, b3.w, acc[0][3]);
      acc[1][0] = fmaf(a1.w, b3.x, acc[1][0]); acc[1][1] = fmaf(a1.w, b3.y, acc[1][1]);
      acc[1][2] = fmaf(a1.w, b3.z, acc[1][2]); acc[1][3] = fmaf(a1.w, b3.w, acc[1][3]);
    }
#pragma unroll
    for (int i = 0; i < 2; ++i)
#pragma unroll
      for (int jj = 0; jj < 4; ++jj) s[i] += __expf(5.0f * acc[i][jj]);
  }
#pragma unroll
  for (int i = 0; i < 2; ++i) {
    for (int off = 1; off < 16; off <<= 1) s[i] += __shfl_xor(s[i], off, 64);
    if (tx == 0) atomicAdd(&S[brow0 + ty * 2 + i], s[i]);
  }
}

__global__ void k_cfinal(const float* __restrict__ Pu, const float* __restrict__ Ps,
                         const float* __restrict__ Su, const float* __restrict__ Ss,
                         float* __restrict__ accs) {
  int gid = blockIdx.x * blockDim.x + threadIdx.x;
  int wave = gid >> 6, lane = gid & 63;
  if (wave >= 2 * Bc) return;
  int loss = wave >> 11, b = wave & (Bc - 1);
  const float* P = loss ? Ps : Pu;
  const float* S = loss ? Ss : Su;
  float2 p = ((const float2*)(P + (size_t)b * D))[lane];
  float pos = p.x * p.x + p.y * p.y;
  for (int m = 1; m < 64; m <<= 1) pos += __shfl_xor(pos, m, 64);
  if (lane == 0) atomicAdd(&accs[1 + loss], logf(S[b]) - 5.0f * pos);
}

__global__ void k_final(const float* __restrict__ accs, float* __restrict__ out) {
  if (threadIdx.x == 0 && blockIdx.x == 0) {
    out[0] = accs[0] / (float)Bc;
    out[1] = 0.5f * (accs[1] + accs[2]) / (float)Bc;
  }
}

// ---------------- launch ----------------
extern "C" void kernel_launch(void* const* d_in, const int* in_sizes, int n_in,
                              void* d_out, int out_size, void* d_ws, size_t ws_size,
                              hipStream_t stream) {
  const float* usersF = (const float*)d_in[0];
  const float* streamersF = (const float*)d_in[1];
  const float* videosF = (const float*)d_in[2];
  const float* linW = (const float*)d_in[3];
  const float* linB = (const float*)d_in[4];
  const int* grows[5] = {(const int*)d_in[5], (const int*)d_in[8], (const int*)d_in[11],
                         (const int*)d_in[14], (const int*)d_in[17]};
  const int* gcols[5] = {(const int*)d_in[6], (const int*)d_in[9], (const int*)d_in[12],
                         (const int*)d_in[15], (const int*)d_in[18]};
  const float* gvals[5] = {(const float*)d_in[7], (const float*)d_in[10], (const float*)d_in[13],
                           (const float*)d_in[16], (const float*)d_in[19]};
  const int* users = (const int*)d_in[20];
  const int* streamers = (const int*)d_in[21];
  int nnz[5] = {in_sizes[5], in_sizes[8], in_sizes[11], in_sizes[14], in_sizes[17]};
  int gn[5] = {N_US, N_UV, N_SV, NUc, NSc};  // us, uv, sv, uva, sva
  float* out = (float*)d_out;

  // ---------- workspace ----------
  char* pb = (char*)d_ws;
  auto allocH = [&](size_t nh) { _Float16* p = (_Float16*)pb; pb += nh * 2; return p; };
  _Float16* L0 = allocH((size_t)N_ALL * D);
  // layer-1 outputs in GLOBAL row space: us 60000 rows (identity),
  // uv 90000 rows (hole at [50000,60000)), sv 40000 rows (global - 50000)
  _Float16* Th0 = allocH((size_t)N_US * D);
  _Float16* Th1 = allocH((size_t)N_ALL * D);
  _Float16* Th2 = allocH((size_t)N_SV * D);
  _Float16* Ac[3] = {allocH((size_t)N_US * D), allocH((size_t)N_UV * D), allocH((size_t)N_SV * D)};
  _Float16* UVsH = allocH((size_t)NSc * D);
  _Float16* SVuH = allocH((size_t)NUc * D);
  pb = (char*)(((uintptr_t)pb + 15) & ~(uintptr_t)15);
  float* Pu = (float*)pb; pb += (size_t)Bc * D * 4;
  float* Ps = (float*)pb; pb += (size_t)Bc * D * 4;
  float* accs = (float*)pb; pb += 16 * 4;
  float* Su = (float*)pb; pb += Bc * 4;
  float* Ss = (float*)pb; pb += Bc * 4;
  int totE = nnz[0] + nnz[1] + nnz[2] + nnz[3] + nnz[4];
  int2* cvAll = (int2*)pb; pb += (size_t)totE * 8;
  int2* ibAll = (int2*)pb; pb += (size_t)totE * 8;
  int* rpAll = (int*)pb;
  int totRP = 0;
  for (int g = 0; g < 5; ++g) totRP += gn[g] + 1;
  pb += (size_t)totRP * 4;
  int* auxAll = (int*)pb; pb += 5 * 128 * 4;

  // ---------- CSR build descriptor ----------
  Bld b;
  int totCBlk = 0;
  {
    int eA = 0, sA = 0, rpO = 0, cvO = 0, bA = 0, cA = 0;
    // col remap local -> L0 global: c += (c>=thr ? add : 0)
    int thrC[5] = {0x7fffffff, NUc, 0, 0x7fffffff, 0x7fffffff};
    int addC[5] = {0, NSc, NUc, 0, 0};
    for (int g = 0; g < 5; ++g) {
      b.rows[g] = grows[g]; b.cols[g] = gcols[g]; b.vals[g] = gvals[g];
      b.thrC[g] = thrC[g]; b.addC[g] = addC[g];
      b.eBase[g] = eA; eA += nnz[g];
      int n1 = gn[g] + 1;
      b.nPlus1[g] = n1;
      b.sBlkBase[g] = sA; sA += (n1 + 1023) / 1024;
      b.cBlkBase[g] = cA; cA += (nnz[g] + CHUNK - 1) / CHUNK;
      b.rp[g] = rpAll + rpO; rpO += n1;
      b.aux[g] = auxAll + g * 128;
      b.cv[g] = cvAll + cvO;
      b.ibuf[g] = ibAll + cvO; cvO += nnz[g];
      b.bktBase[g] = bA; bA += (gn[g] + BW - 1) / BW;
    }
    b.eBase[5] = eA;
    b.sBlkBase[5] = sA;
    b.cBlkBase[5] = cA;
    b.bktBase[5] = bA;
    totCBlk = cA;
  }
  int totBlk = b.sBlkBase[5];
  int totBkt = b.bktBase[5];
  int* bhistAll = (int*)pb; pb += (size_t)totCBlk * NBH * 4;
  b.bhist = bhistAll;

  // ---------- keys (JAX threefry, partitionable fold-in split) ----------
  uint32_t kus[2], kuv[2], ksv[2], kauv[2], kasv[2];
  threefry(0u, 42u, 0u, 0u, kus[0], kus[1]);
  threefry(0u, 42u, 0u, 1u, kuv[0], kuv[1]);
  threefry(0u, 42u, 0u, 2u, ksv[0], ksv[1]);
  threefry(0u, 42u, 0u, 3u, kauv[0], kauv[1]);
  threefry(0u, 42u, 0u, 4u, kasv[0], kasv[1]);
  uint32_t kusL[2][2], kuvL[2][2], ksvL[2][2];
  for (uint32_t i = 0; i < 2; ++i) {
    threefry(kus[0], kus[1], 0u, i, kusL[i][0], kusL[i][1]);
    threefry(kuv[0], kuv[1], 0u, i, kuvL[i][0], kuvL[i][1]);
    threefry(ksv[0], ksv[1], 0u, i, ksvL[i][0], ksvL[i][1]);
  }

  // ---------- CSR build (deterministic two-level scatter) + L0 table ----------
  hipMemsetAsync(rpAll, 0, (size_t)totRP * sizeof(int), stream);
  int l0Blocks = (N_ALL * (D / 4) + 255) / 256;
  k_histl0<<<(unsigned)(totCBlk + l0Blocks), 256, 0, stream>>>(b, usersF, streamersF, videosF,
                                                               L0, totCBlk);
  k_scan1f<<<(unsigned)totBlk, 1024, 0, stream>>>(b);
  k_scan2f<<<5, 64, 0, stream>>>(b);
  k_scan3f<<<(unsigned)totBlk, 1024, 0, stream>>>(b);
  k_bscan<<<(unsigned)(((size_t)totBkt * 64 + 255) / 256), 256, 0, stream>>>(b);
  k_bscat<<<(unsigned)totCBlk, 256, 0, stream>>>(b);
  k_scatl2<<<(unsigned)totBkt, 256, 0, stream>>>(b);

  // ---------- propagate layers (fused over us/uv/sv) ----------
  GP p1, p2;
  const uint32_t* kL1[3] = {kusL[0], kuvL[0], ksvL[0]};
  const uint32_t* kL2[3] = {kusL[1], kuvL[1], ksvL[1]};
  int rB[4] = {0, N_US, N_US + N_UV, N_US + N_UV + N_SV};
  // per-graph row remap rl -> global row gr
  int rThr[3] = {0x7fffffff, NUc, 0};
  int rAdd[3] = {0, NSc, NUc};
  // dst pointers pre-offset so dst[gr] is correct
  _Float16* dstP[3] = {Th0, Th1, Th2 - (size_t)NUc * D};
  // layer-2 gather sources pre-offset so src[(gcol<<8)] is correct
  const char* src2[3] = {(const char*)Th0, (const char*)Th1,
                         (const char*)Th2 - (size_t)NUc * D * 2};
  for (int g = 0; g < 3; ++g) {
    p1.rp[g] = b.rp[g]; p1.cv[g] = b.cv[g];
    p1.src[g] = (const char*)L0; p1.accIn[g] = L0; p1.accOut[g] = Ac[g]; p1.dst[g] = dstP[g];
    p1.k0[g] = kL1[g][0]; p1.k1[g] = kL1[g][1];
    p1.rowThr[g] = rThr[g]; p1.rowAdd[g] = rAdd[g];
    p1.rBase[g] = rB[g];
    p2.rp[g] = b.rp[g]; p2.cv[g] = b.cv[g];
    p2.src[g] = src2[g]; p2.accIn[g] = Ac[g]; p2.accOut[g] = Ac[g]; p2.dst[g] = nullptr;
    p2.k0[g] = kL2[g][0]; p2.k1[g] = kL2[g][1];
    p2.rowThr[g] = 0x7fffffff; p2.rowAdd[g] = 0;
    p2.rBase[g] = rB[g];
  }
  p1.rBase[3] = rB[3]; p2.rBase[3] = rB[3];
  p1.div = 1.0f; p2.div = 3.0f;
  unsigned gpropBlocks = (unsigned)(((size_t)rB[3] * 64 + 255) / 256);
  k_gprop3<<<gpropBlocks, 256, 0, stream>>>(p1);
  k_gprop3<<<gpropBlocks, 256, 0, stream>>>(p2);

  // ---------- aggregates (fused) ----------
  GA ga;
  ga.rp[0] = b.rp[3]; ga.cv[0] = b.cv[3];
  ga.src[0] = (const char*)(Ac[2] + (size_t)NSc * D);  // SV video part (cols 0..NV)
  ga.dst[0] = SVuH; ga.k0[0] = kauv[0]; ga.k1[0] = kauv[1];
  ga.rp[1] = b.rp[4]; ga.cv[1] = b.cv[4];
  ga.src[1] = (const char*)(Ac[1] + (size_t)NUc * D);  // UV video part
  ga.dst[1] = UVsH; ga.k0[1] = kasv[0]; ga.k1[1] = kasv[1];
  ga.rBase[0] = 0; ga.rBase[1] = NUc; ga.rBase[2] = NUc + NSc;
  k_gagg2<<<(unsigned)(((size_t)(NUc + NSc) * 64 + 255) / 256), 256, 0, stream>>>(ga);

  // ---------- attention + losses ----------
  k_mga<<<(unsigned)((NUc + NSc + 3) / 4), 256, 0, stream>>>(Ac[0], Ac[1], UVsH, SVuH, Ac[2],
                                                             linW, linB);
  hipMemsetAsync(accs, 0, (size_t)(16 + 2 * Bc) * sizeof(float), stream);
  k_batch<<<(unsigned)((Bc + 3) / 4), 256, 0, stream>>>(Ac[0], users, streamers, Pu, Ps, accs);
  k_cgemm<<<dim3(Bc / 32, 4, 2), 256, 0, stream>>>(Pu, Ps, Su, Ss);
  k_cfinal<<<(unsigned)((2 * Bc + 3) / 4), 256, 0, stream>>>(Pu, Ps, Su, Ss, accs);
  k_final<<<1, 64, 0, stream>>>(accs, out);
}

// Round 12
// 827.985 us; speedup vs baseline: 1.1174x; 1.0458x over previous
//
#include <hip/hip_runtime.h>
#include <stdint.h>

#define D 128
constexpr int NUc = 50000, NSc = 10000, NVc = 30000, Bc = 2048;
constexpr int N_US = 60000, N_UV = 80000, N_SV = 40000, N_ALL = 90000;
constexpr int BW = 64;       // bucket row width (shift 6)
constexpr int NBH = 1280;    // max buckets per graph (uv: 80000/64=1250)
constexpr int CHUNK = 4096;  // edges per scatter block
constexpr int CAPE = 6144;   // LDS staging capacity (edges)

typedef _Float16 h2v __attribute__((ext_vector_type(2)));
typedef _Float16 h4v __attribute__((ext_vector_type(4)));

// ---------------- Threefry-2x32 (JAX) ----------------
__host__ __device__ inline void threefry(uint32_t k0, uint32_t k1, uint32_t x0, uint32_t x1,
                                         uint32_t& o0, uint32_t& o1) {
  uint32_t ks2 = k0 ^ k1 ^ 0x1BD11BDAu;
  uint32_t v0 = x0 + k0, v1 = x1 + k1;
#define TFR(r) { v0 += v1; v1 = (v1 << (r)) | (v1 >> (32 - (r))); v1 ^= v0; }
  TFR(13) TFR(15) TFR(26) TFR(6)   v0 += k1;  v1 += ks2 + 1u;
  TFR(17) TFR(29) TFR(16) TFR(24)  v0 += ks2; v1 += k0 + 2u;
  TFR(13) TFR(15) TFR(26) TFR(6)   v0 += k0;  v1 += k1 + 3u;
  TFR(17) TFR(29) TFR(16) TFR(24)  v0 += k1;  v1 += ks2 + 4u;
  TFR(13) TFR(15) TFR(26) TFR(6)   v0 += ks2; v1 += k0 + 5u;
#undef TFR
  o0 = v0; o1 = v1;
}

__device__ __forceinline__ float unif01(uint32_t k0, uint32_t k1, uint32_t j) {
  uint32_t a, b;
  threefry(k0, k1, 0u, j, a, b);
  uint32_t bits = a ^ b;
  return __uint_as_float(0x3F800000u | (bits >> 9)) - 1.0f;
}

// ---------------- fused CSR build over 5 graphs ----------------
struct Bld {
  const int* rows[5]; const int* cols[5]; const float* vals[5];
  int* rp[5]; int* aux[5];
  int2* cv[5]; int2* ibuf[5];
  int* bhist;           // [totCBlk][NBH]
  int eBase[6];         // cumulative edges
  int sBlkBase[6];      // cumulative scan blocks
  int cBlkBase[6];      // cumulative chunk blocks
  int bktBase[6];       // cumulative buckets
  int nPlus1[5];
  int thrC[5], addC[5]; // col remap local->L0-global: c += (c>=thr ? add : 0)
};

// fused: per-chunk histogram (rp global atomics + LDS bucket hist -> bhist)
// + layer-0 fp16 table conversion in trailing blocks
__global__ __launch_bounds__(256) void k_histl0(Bld b, const float* __restrict__ u,
                                                const float* __restrict__ s,
                                                const float* __restrict__ v,
                                                _Float16* __restrict__ L0, int cBlkTot) {
  __shared__ int h[NBH];
  if ((int)blockIdx.x >= cBlkTot) {
    int gid = ((int)blockIdx.x - cBlkTot) * 256 + threadIdx.x;  // h4v units
    const int tot = N_ALL * (D / 4);
    if (gid >= tot) return;
    int r = gid >> 5, c4 = gid & 31;
    const float* src = (r < NUc) ? u + (size_t)r * D
                     : (r < NUc + NSc) ? s + (size_t)(r - NUc) * D
                                       : v + (size_t)(r - NUc - NSc) * D;
    float4 x = ((const float4*)src)[c4];
    ((h4v*)L0)[gid] = h4v{(_Float16)x.x, (_Float16)x.y, (_Float16)x.z, (_Float16)x.w};
    return;
  }
  int blk = blockIdx.x;
  int g = 0;
  while (blk >= b.cBlkBase[g + 1]) ++g;
  int lblk = blk - b.cBlkBase[g];
  int nbkt = b.bktBase[g + 1] - b.bktBase[g];
  int tid = threadIdx.x;
  for (int i = tid; i < nbkt; i += 256) h[i] = 0;
  __syncthreads();
  int nnzg = b.eBase[g + 1] - b.eBase[g];
  int e0 = lblk * CHUNK;
  int eEnd = min(e0 + CHUNK, nnzg);
  int* rp = b.rp[g];
  const int* rows = b.rows[g];
  for (int e = e0 + tid; e < eEnd; e += 256) {
    int row = __builtin_nontemporal_load(rows + e);
    atomicAdd(&rp[row + 1], 1);
    atomicAdd(&h[row >> 6], 1);
  }
  __syncthreads();
  int* outp = b.bhist + (size_t)blk * NBH;
  for (int i = tid; i < nbkt; i += 256) outp[i] = h[i];
}

__global__ __launch_bounds__(1024) void k_scan1f(Bld b) {
  __shared__ int wsum[16];
  int blk = blockIdx.x;
  int g = 0;
  while (blk >= b.sBlkBase[g + 1]) ++g;
  int lb = blk - b.sBlkBase[g];
  int n = b.nPlus1[g];
  int* data = b.rp[g];
  int tid = threadIdx.x, lane = tid & 63, w = tid >> 6;
  int i = lb * 1024 + tid;
  int x = (i < n) ? data[i] : 0;
  for (int off = 1; off < 64; off <<= 1) {
    int t = __shfl_up(x, off, 64);
    if (lane >= off) x += t;
  }
  if (lane == 63) wsum[w] = x;
  __syncthreads();
  if (w == 0 && lane < 16) {
    int s = wsum[lane];
    for (int off = 1; off < 16; off <<= 1) {
      int t = __shfl_up(s, off, 64);
      if (lane >= off) s += t;
    }
    wsum[lane] = s;
  }
  __syncthreads();
  int woff = (w > 0) ? wsum[w - 1] : 0;
  if (i < n) data[i] = x + woff;
  if (tid == 1023) b.aux[g][lb] = x + woff;
}

__global__ void k_scan2f(Bld b) {
  int g = blockIdx.x;
  int nb = b.sBlkBase[g + 1] - b.sBlkBase[g];
  int* aux = b.aux[g];
  int lane = threadIdx.x;  // 64 threads
  int carry = 0;
  for (int base = 0; base < nb; base += 64) {
    int i = base + lane;
    int v = (i < nb) ? aux[i] : 0;
    for (int off = 1; off < 64; off <<= 1) {
      int t = __shfl_up(v, off, 64);
      if (lane >= off) v += t;
    }
    if (i < nb) aux[i] = v + carry;
    carry += __shfl(v, 63, 64);
  }
}

__global__ __launch_bounds__(1024) void k_scan3f(Bld b) {
  int blk = blockIdx.x;
  int g = 0;
  while (blk >= b.sBlkBase[g + 1]) ++g;
  int lb = blk - b.sBlkBase[g];
  if (lb == 0) return;
  int i = lb * 1024 + threadIdx.x;
  if (i < b.nPlus1[g]) b.rp[g][i] += b.aux[g][lb - 1];
}

// one wave per bucket: scan per-block counts -> exclusive global bases
__global__ void k_bscan(Bld b) {
  int gid = blockIdx.x * blockDim.x + threadIdx.x;
  int w = gid >> 6, lane = gid & 63;
  if (w >= b.bktBase[5]) return;
  int g = 0;
  while (w >= b.bktBase[g + 1]) ++g;
  int lb = w - b.bktBase[g];
  int carry = b.rp[g][lb * BW];  // bucket start in graph-local CSR space
  int blk0 = b.cBlkBase[g], nblk = b.cBlkBase[g + 1] - blk0;
  for (int t = 0; t < nblk; t += 64) {
    int i = t + lane;
    int v = (i < nblk) ? b.bhist[(size_t)(blk0 + i) * NBH + lb] : 0;
    int x = v;
    for (int off = 1; off < 64; off <<= 1) {
      int tt = __shfl_up(x, off, 64);
      if (lane >= off) x += tt;
    }
    if (i < nblk) b.bhist[(size_t)(blk0 + i) * NBH + lb] = x - v + carry;
    carry += __shfl(x, 63, 64);
  }
}

// deterministic bucket scatter (LDS cursors, no global atomics)
// emits {global_col | rowlow<<17, val as duplicated f16x2}
__global__ __launch_bounds__(256) void k_bscat(Bld b) {
  __shared__ int cur[NBH];
  int blk = blockIdx.x;
  int g = 0;
  while (blk >= b.cBlkBase[g + 1]) ++g;
  int lblk = blk - b.cBlkBase[g];
  int nbkt = b.bktBase[g + 1] - b.bktBase[g];
  int tid = threadIdx.x;
  const int* bh = b.bhist + (size_t)blk * NBH;
  for (int i = tid; i < nbkt; i += 256) cur[i] = bh[i];
  __syncthreads();
  int nnzg = b.eBase[g + 1] - b.eBase[g];
  int e0 = lblk * CHUNK;
  int eEnd = min(e0 + CHUNK, nnzg);
  int2* ib = b.ibuf[g];
  int thr = b.thrC[g], add = b.addC[g];
  const int* rows = b.rows[g];
  const int* cols = b.cols[g];
  const float* vals = b.vals[g];
  for (int e = e0 + tid; e < eEnd; e += 256) {
    int row = __builtin_nontemporal_load(rows + e);
    int c = __builtin_nontemporal_load(cols + e);
    float v = __builtin_nontemporal_load(vals + e);
    c += (c >= thr) ? add : 0;
    uint32_t hb = (uint32_t)__builtin_bit_cast(unsigned short, (_Float16)v);
    int pos = atomicAdd(&cur[row >> 6], 1);
    ib[pos] = make_int2(c | ((row & (BW - 1)) << 17), (int)(hb | (hb << 16)));
  }
}

// level-2: within-bucket row ordering via LDS cursors + coalesced stream-out
__global__ __launch_bounds__(256) void k_scatl2(Bld b) {
  __shared__ int lcur[BW];
  __shared__ int2 stg[CAPE];
  int bid = blockIdx.x;
  int g = 0;
  while (bid >= b.bktBase[g + 1]) ++g;
  int lb = bid - b.bktBase[g];
  int n = b.nPlus1[g] - 1;
  int r0 = lb * BW;
  int rowsInB = min(BW, n - r0);
  const int* rp = b.rp[g];
  int segStart = rp[r0];
  int segLen = rp[r0 + rowsInB] - segStart;
  int tid = threadIdx.x;
  if (tid < rowsInB) lcur[tid] = rp[r0 + tid] - segStart;
  __syncthreads();
  const int2* ib = b.ibuf[g];
  int2* cv = b.cv[g];
  for (int i = tid; i < segLen; i += 256) {
    unsigned long long raw =
        __builtin_nontemporal_load((const unsigned long long*)(ib + segStart + i));
    int vx = (int)(uint32_t)raw;
    int vy = (int)(uint32_t)(raw >> 32);
    int rowlow = ((uint32_t)vx) >> 17;
    int2 outv = make_int2(vx & 0x1FFFF, vy);
    int lpos = atomicAdd(&lcur[rowlow], 1);
    if (lpos < CAPE) stg[lpos] = outv;
    else cv[segStart + lpos] = outv;
  }
  __syncthreads();
  int lim = min(segLen, CAPE);
  for (int i = tid; i < lim; i += 256) cv[segStart + i] = stg[i];
}

// ---------------- gather core: 2 edges/wave, 8-edge unroll (4 chains, 4x MLP) ----------------
// lanes 0-31 handle even edges, lanes 32-63 odd edges; each lane loads 8B (4 cols).
__device__ __forceinline__ void gather_row(const int* __restrict__ rp,
                                           const int2* __restrict__ cv,
                                           const char* __restrict__ spc, int rl, int lane,
                                           float& fx, float& fy) {
  int s = rp[rl], e = rp[rl + 1];
  int half = lane >> 5;
  uint32_t lcol = (uint32_t)(lane & 31) << 3;  // byte offset within 256B row
  h4v a0 = {0, 0, 0, 0}, a1 = {0, 0, 0, 0}, a2 = {0, 0, 0, 0}, a3 = {0, 0, 0, 0};
  int k = s;
  for (; k + 7 < e; k += 8) {
    int2 q0 = cv[k + half];
    int2 q1 = cv[k + 2 + half];
    int2 q2 = cv[k + 4 + half];
    int2 q3 = cv[k + 6 + half];
    h4v x0 = *(const h4v*)(spc + ((uint32_t)q0.x << 8) + lcol);
    h4v x1 = *(const h4v*)(spc + ((uint32_t)q1.x << 8) + lcol);
    h4v x2 = *(const h4v*)(spc + ((uint32_t)q2.x << 8) + lcol);
    h4v x3 = *(const h4v*)(spc + ((uint32_t)q3.x << 8) + lcol);
    uint2 d0 = {(uint32_t)q0.y, (uint32_t)q0.y};
    uint2 d1 = {(uint32_t)q1.y, (uint32_t)q1.y};
    uint2 d2 = {(uint32_t)q2.y, (uint32_t)q2.y};
    uint2 d3 = {(uint32_t)q3.y, (uint32_t)q3.y};
    a0 += x0 * __builtin_bit_cast(h4v, d0);
    a1 += x1 * __builtin_bit_cast(h4v, d1);
    a2 += x2 * __builtin_bit_cast(h4v, d2);
    a3 += x3 * __builtin_bit_cast(h4v, d3);
  }
  for (; k + 3 < e; k += 4) {
    int2 q0 = cv[k + half];
    int2 q1 = cv[k + 2 + half];
    h4v x0 = *(const h4v*)(spc + ((uint32_t)q0.x << 8) + lcol);
    h4v x1 = *(const h4v*)(spc + ((uint32_t)q1.x << 8) + lcol);
    uint2 d0 = {(uint32_t)q0.y, (uint32_t)q0.y};
    uint2 d1 = {(uint32_t)q1.y, (uint32_t)q1.y};
    a0 += x0 * __builtin_bit_cast(h4v, d0);
    a1 += x1 * __builtin_bit_cast(h4v, d1);
  }
  for (; k < e; k += 2) {
    int ke = k + half;
    int idx = (ke < e) ? ke : (e - 1);
    int2 q = cv[idx];
    uint32_t vv = (ke < e) ? (uint32_t)q.y : 0u;
    h4v x = *(const h4v*)(spc + ((uint32_t)q.x << 8) + lcol);
    uint2 dd = {vv, vv};
    a0 += x * __builtin_bit_cast(h4v, dd);
  }
  a0 += a2;
  a1 += a3;
  float f0 = (float)a0.x + (float)a1.x;
  float f1 = (float)a0.y + (float)a1.y;
  float f2 = (float)a0.z + (float)a1.z;
  float f3 = (float)a0.w + (float)a1.w;
  f0 += __shfl_xor(f0, 32, 64);
  f1 += __shfl_xor(f1, 32, 64);
  f2 += __shfl_xor(f2, 32, 64);
  f3 += __shfl_xor(f3, 32, 64);
  int srcl = lane >> 1;  // lane srcl holds cols [4*(srcl&31) .. +4)
  float v0 = __shfl(f0, srcl, 64);
  float v1 = __shfl(f1, srcl, 64);
  float v2 = __shfl(f2, srcl, 64);
  float v3 = __shfl(f3, srcl, 64);
  fx = (lane & 1) ? v2 : v0;
  fy = (lane & 1) ? v3 : v1;
}

// ---------------- fused propagate layer over 3 graphs ----------------
struct GP {
  const int* rp[3]; const int2* cv[3];
  const char* src[3];        // gather source (pre-offset to global-col space)
  const _Float16* accIn[3];  // indexed by gr
  _Float16* accOut[3];       // indexed by rl
  _Float16* dst[3];          // indexed by gr (pre-offset); null on layer 2
  uint32_t k0[3], k1[3];
  int rowThr[3], rowAdd[3];  // gr = rl + (rl>=thr ? add : 0)
  int rBase[4];
  float div;
};

__global__ void k_gprop3(GP p) {
  int gid = blockIdx.x * blockDim.x + threadIdx.x;
  int r = gid >> 6, lane = gid & 63;
  if (r >= p.rBase[3]) return;
  int g = 0;
  while (r >= p.rBase[g + 1]) ++g;
  int rl = r - p.rBase[g];
  float fx, fy;
  gather_row(p.rp[g], p.cv[g], p.src[g], rl, lane, fx, fy);
  uint32_t j0 = (uint32_t)rl * D + (uint32_t)lane * 2;
  float u0 = unif01(p.k0[g], p.k1[g], j0);
  float u1 = unif01(p.k0[g], p.k1[g], j0 + 1u);
  float s2 = u0 * u0 + u1 * u1;
  for (int m = 1; m < 64; m <<= 1) s2 += __shfl_xor(s2, m, 64);
  float nn = fmaxf(sqrtf(s2), 1e-12f);
  float sg0 = (fx > 0.f) ? 1.f : ((fx < 0.f) ? -1.f : 0.f);
  float sg1 = (fy > 0.f) ? 1.f : ((fy < 0.f) ? -1.f : 0.f);
  float nf0 = fx + sg0 * (u0 / nn) * 0.1f;
  float nf1 = fy + sg1 * (u1 / nn) * 0.1f;
  float fs = nf0 * nf0 + nf1 * nf1;
  for (int m = 1; m < 64; m <<= 1) fs += __shfl_xor(fs, m, 64);
  float fn = fmaxf(sqrtf(fs), 1e-12f);
  int gr = rl + ((rl >= p.rowThr[g]) ? p.rowAdd[g] : 0);
  h2v ai = ((const h2v*)p.accIn[g])[(size_t)gr * (D / 2) + lane];
  float ax = ((float)ai.x + nf0 / fn) / p.div;
  float ay = ((float)ai.y + nf1 / fn) / p.div;
  ((h2v*)p.accOut[g])[(size_t)rl * (D / 2) + lane] = h2v{(_Float16)ax, (_Float16)ay};
  if (p.dst[g])
    ((h2v*)p.dst[g])[(size_t)gr * (D / 2) + lane] = h2v{(_Float16)nf0, (_Float16)nf1};
}

// ---------------- fused aggregate over 2 graphs ----------------
struct GA {
  const int* rp[2]; const int2* cv[2];
  const char* src[2]; _Float16* dst[2];
  uint32_t k0[2], k1[2];
  int rBase[3];
};

__global__ void k_gagg2(GA a) {
  int gid = blockIdx.x * blockDim.x + threadIdx.x;
  int r = gid >> 6, lane = gid & 63;
  if (r >= a.rBase[2]) return;
  int g = (r >= a.rBase[1]) ? 1 : 0;
  int rl = r - a.rBase[g];
  float fx, fy;
  gather_row(a.rp[g], a.cv[g], a.src[g], rl, lane, fx, fy);
  uint32_t j0 = (uint32_t)rl * D + (uint32_t)lane * 2;
  float u0 = unif01(a.k0[g], a.k1[g], j0);
  float u1 = unif01(a.k0[g], a.k1[g], j0 + 1u);
  float s2 = u0 * u0 + u1 * u1;
  for (int m = 1; m < 64; m <<= 1) s2 += __shfl_xor(s2, m, 64);
  float nn = fmaxf(sqrtf(s2), 1e-12f);
  float sg0 = (fx > 0.f) ? 1.f : ((fx < 0.f) ? -1.f : 0.f);
  float sg1 = (fy > 0.f) ? 1.f : ((fy < 0.f) ? -1.f : 0.f);
  ((h2v*)a.dst[g])[(size_t)rl * (D / 2) + lane] =
      h2v{(_Float16)(fx + sg0 * (u0 / nn) * 0.1f), (_Float16)(fy + sg1 * (u1 / nn) * 0.1f)};
}

// ---------------- MGA attention (fp16 in/out, in-place into e0buf) ----------------
__global__ void k_mga(_Float16* __restrict__ e0buf, const _Float16* __restrict__ UVa,
                      const _Float16* __restrict__ UVs, const _Float16* __restrict__ SVu,
                      const _Float16* __restrict__ SVa, const float* __restrict__ w,
                      const float* __restrict__ bptr) {
  int gid = blockIdx.x * blockDim.x + threadIdx.x;
  int wave = gid >> 6, lane = gid & 63;
  int n = NUc + NSc;
  if (wave >= n) return;
  const _Float16* e1 = (wave < NUc) ? UVa + (size_t)wave * D : UVs + (size_t)(wave - NUc) * D;
  const _Float16* e2 = (wave < NUc) ? SVu + (size_t)wave * D : SVa + (size_t)(wave - NUc) * D;
  _Float16* e0 = e0buf + (size_t)wave * D;
  int c = lane * 2;
  h2v h0 = *(const h2v*)(e0 + c), h1 = *(const h2v*)(e1 + c), h2_ = *(const h2v*)(e2 + c);
  float2 v0 = {(float)h0.x, (float)h0.y};
  float2 v1 = {(float)h1.x, (float)h1.y};
  float2 v2 = {(float)h2_.x, (float)h2_.y};
  float2 wl = *(const float2*)(w + c);
  float2 wh = *(const float2*)(w + D + c);
  float d00 = v0.x * wl.x + v0.y * wl.y;
  float c0 = v0.x * wh.x + v0.y * wh.y;
  float c1 = v1.x * wh.x + v1.y * wh.y;
  float c2 = v2.x * wh.x + v2.y * wh.y;
  for (int m = 1; m < 64; m <<= 1) {
    d00 += __shfl_xor(d00, m, 64);
    c0 += __shfl_xor(c0, m, 64);
    c1 += __shfl_xor(c1, m, 64);
    c2 += __shfl_xor(c2, m, 64);
  }
  float b = bptr[0];
  float l0 = d00 + c0 + b, l1 = d00 + c1 + b, l2v = d00 + c2 + b;
  float mx = fmaxf(l0, fmaxf(l1, l2v));
  float a0 = expf(l0 - mx), a1 = expf(l1 - mx), a2 = expf(l2v - mx);
  float s = a0 + a1 + a2;
  a0 /= s; a1 /= s; a2 /= s;
  float ox = a0 * v0.x + a1 * v1.x + a2 * v2.x;
  float oy = a0 * v0.y + a1 * v1.y + a2 * v2.y;
  *(h2v*)(e0 + c) = h2v{(_Float16)ox, (_Float16)oy};
}

// ---------------- batch gather: BPR + normalized P rows ----------------
__global__ void k_batch(const _Float16* __restrict__ reps, const int* __restrict__ users,
                        const int* __restrict__ streamers, float* __restrict__ Pu,
                        float* __restrict__ Ps, float* __restrict__ accs) {
  int gid = blockIdx.x * blockDim.x + threadIdx.x;
  int wave = gid >> 6, lane = gid & 63;
  if (wave >= Bc) return;
  int u = users[wave];
  int s0 = streamers[wave * 2], s1 = streamers[wave * 2 + 1];
  h2v uh = ((const h2v*)(reps + (size_t)u * D))[lane];
  h2v ah = ((const h2v*)(reps + (size_t)(NUc + s0) * D))[lane];
  h2v ch = ((const h2v*)(reps + (size_t)(NUc + s1) * D))[lane];
  float2 uv = {(float)uh.x, (float)uh.y};
  float2 av = {(float)ah.x, (float)ah.y};
  float2 cv = {(float)ch.x, (float)ch.y};
  float p0 = uv.x * av.x + uv.y * av.y;
  float p1 = uv.x * cv.x + uv.y * cv.y;
  float un = uv.x * uv.x + uv.y * uv.y;
  float an = av.x * av.x + av.y * av.y;
  for (int m = 1; m < 64; m <<= 1) {
    p0 += __shfl_xor(p0, m, 64);
    p1 += __shfl_xor(p1, m, 64);
    un += __shfl_xor(un, m, 64);
    an += __shfl_xor(an, m, 64);
  }
  if (lane == 0) {
    float t = p0 - p1;
    float term = fmaxf(-t, 0.f) + log1pf(expf(-fabsf(t)));  // -log_sigmoid(t)
    atomicAdd(&accs[0], term);
  }
  float und = fmaxf(sqrtf(un), 1e-12f);
  float andv = fmaxf(sqrtf(an), 1e-12f);
  ((float2*)(Pu + (size_t)wave * D))[lane] = float2{uv.x / und, uv.y / und};
  ((float2*)(Ps + (size_t)wave * D))[lane] = float2{av.x / andv, av.y / andv};
}

// ---------------- contrastive GEMM: S[b] += sum_j exp(5*dot) ----------------
__global__ __launch_bounds__(256) void k_cgemm(const float* __restrict__ Pu,
                                               const float* __restrict__ Ps,
                                               float* __restrict__ Su,
                                               float* __restrict__ Ss) {
  const float* P = blockIdx.z ? Ps : Pu;
  float* S = blockIdx.z ? Ss : Su;
  __shared__ float A[32][132];
  __shared__ float BT[128][68];
  int tid = threadIdx.x;
  int tx = tid & 15, ty = tid >> 4;
  int brow0 = blockIdx.x * 32;
  int j0 = blockIdx.y * 512;
#pragma unroll
  for (int i = 0; i < 4; ++i) {
    int idx = tid + i * 256;
    int r = idx >> 5, c4 = idx & 31;
    float4 v = ((const float4*)(P + (size_t)(brow0 + r) * D))[c4];
    *(float4*)&A[r][c4 * 4] = v;
  }
  float s[2] = {0.f, 0.f};
  for (int jt = 0; jt < 8; ++jt) {
    __syncthreads();
#pragma unroll
    for (int i = 0; i < 8; ++i) {
      int idx = tid + i * 256;
      int r = idx >> 5, c4 = idx & 31;
      float4 v = ((const float4*)(P + (size_t)(j0 + jt * 64 + r) * D))[c4];
      BT[c4 * 4 + 0][r] = v.x;
      BT[c4 * 4 + 1][r] = v.y;
      BT[c4 * 4 + 2][r] = v.z;
      BT[c4 * 4 + 3][r] = v.w;
    }
    __syncthreads();
    float acc[2][4] = {};
    for (int k = 0; k < 128; k += 4) {
      float4 a0 = *(const float4*)&A[ty * 2 + 0][k];
      float4 a1 = *(const float4*)&A[ty * 2 + 1][k];
      float4 b0 = *(const float4*)&BT[k + 0][tx * 4];
      float4 b1 = *(const float4*)&BT[k + 1][tx * 4];
      float4 b2 = *(const float4*)&BT[k + 2][tx * 4];
      float4 b3 = *(const float4*)&BT[k + 3][tx * 4];
      acc[0][0] = fmaf(a0.x, b0.x, acc[0][0]); acc[0][1] = fmaf(a0.x, b0.y, acc[0][1]);
      acc[0][2] = fmaf(a0.x, b0.z, acc[0][2]); acc[0][3] = fmaf(a0.x, b0.w, acc[0][3]);
      acc[1][0] = fmaf(a1.x, b0.x, acc[1][0]); acc[1][1] = fmaf(a1.x, b0.y, acc[1][1]);
      acc[1][2] = fmaf(a1.x, b0.z, acc[1][2]); acc[1][3] = fmaf(a1.x, b0.w, acc[1][3]);
      acc[0][0] = fmaf(a0.y, b1.x, acc[0][0]); acc[0][1] = fmaf(a0.y, b1.y, acc[0][1]);
      acc[0][2] = fmaf(a0.y, b1.z, acc[0][2]); acc[0][3] = fmaf(a0.y, b1.w, acc[0][3]);
      acc[1][0] = fmaf(a1.y, b1.x, acc[1][0]); acc[1][1] = fmaf(a1.y, b1.y, acc[1][1]);
      acc[1][2] = fmaf(a1.y, b1.z, acc[1][2]); acc[1][3] = fmaf(a1.y, b1.w, acc[1][3]);
      acc[0][0] = fmaf(a0.z, b2.x, acc[0][0]); acc[0][1] = fmaf(a0.z, b2.y, acc[0][1]);
      acc[0][2] = fmaf(a0.z, b2.z, acc[0][2]); acc[0][3] = fmaf(a0.z, b2.w, acc[0][3]);
      acc[1][0] = fmaf(a1.z, b2.x, acc[1][0]); acc[1][1] = fmaf(a1.z, b2.y, acc[1][1]);
      acc[1][2] = fmaf(a1.z, b2.z, acc[1][2]); acc[1][3] = fmaf(a1.z, b2.w, acc[1][3]);
      acc[0][0] = fmaf(a0.w, b3.x, acc[0][0]); acc[0][1] = fmaf(a0.w, b3.y, acc[0][1]);
      acc[0][2] = fmaf(a0.w, b3.z, acc[0][2]); acc[0][3] = fmaf(a0.w, b3.w, acc[0][3]);
      acc[1][0] = fmaf(a1.w, b3.x, acc[1][0]); acc[1][1] = fmaf(a1.w, b3.y, acc[1][1]);
      acc[1][2] = fmaf(a1.w, b3.z, acc[1][2]); acc[1][3] = fmaf(a1.w, b3.w, acc[1][3]);
    }
#pragma unroll
    for (int i = 0; i < 2; ++i)
#pragma unroll
      for (int jj = 0; jj < 4; ++jj) s[i] += __expf(5.0f * acc[i][jj]);
  }
#pragma unroll
  for (int i = 0; i < 2; ++i) {
    for (int off = 1; off < 16; off <<= 1) s[i] += __shfl_xor(s[i], off, 64);
    if (tx == 0) atomicAdd(&S[brow0 + ty * 2 + i], s[i]);
  }
}

__global__ void k_cfinal(const float* __restrict__ Pu, const float* __restrict__ Ps,
                         const float* __restrict__ Su, const float* __restrict__ Ss,
                         float* __restrict__ accs) {
  int gid = blockIdx.x * blockDim.x + threadIdx.x;
  int wave = gid >> 6, lane = gid & 63;
  if (wave >= 2 * Bc) return;
  int loss = wave >> 11, b = wave & (Bc - 1);
  const float* P = loss ? Ps : Pu;
  const float* S = loss ? Ss : Su;
  float2 p = ((const float2*)(P + (size_t)b * D))[lane];
  float pos = p.x * p.x + p.y * p.y;
  for (int m = 1; m < 64; m <<= 1) pos += __shfl_xor(pos, m, 64);
  if (lane == 0) atomicAdd(&accs[1 + loss], logf(S[b]) - 5.0f * pos);
}

__global__ void k_final(const float* __restrict__ accs, float* __restrict__ out) {
  if (threadIdx.x == 0 && blockIdx.x == 0) {
    out[0] = accs[0] / (float)Bc;
    out[1] = 0.5f * (accs[1] + accs[2]) / (float)Bc;
  }
}

// ---------------- launch ----------------
extern "C" void kernel_launch(void* const* d_in, const int* in_sizes, int n_in,
                              void* d_out, int out_size, void* d_ws, size_t ws_size,
                              hipStream_t stream) {
  const float* usersF = (const float*)d_in[0];
  const float* streamersF = (const float*)d_in[1];
  const float* videosF = (const float*)d_in[2];
  const float* linW = (const float*)d_in[3];
  const float* linB = (const float*)d_in[4];
  const int* grows[5] = {(const int*)d_in[5], (const int*)d_in[8], (const int*)d_in[11],
                         (const int*)d_in[14], (const int*)d_in[17]};
  const int* gcols[5] = {(const int*)d_in[6], (const int*)d_in[9], (const int*)d_in[12],
                         (const int*)d_in[15], (const int*)d_in[18]};
  const float* gvals[5] = {(const float*)d_in[7], (const float*)d_in[10], (const float*)d_in[13],
                           (const float*)d_in[16], (const float*)d_in[19]};
  const int* users = (const int*)d_in[20];
  const int* streamers = (const int*)d_in[21];
  int nnz[5] = {in_sizes[5], in_sizes[8], in_sizes[11], in_sizes[14], in_sizes[17]};
  int gn[5] = {N_US, N_UV, N_SV, NUc, NSc};  // us, uv, sv, uva, sva
  float* out = (float*)d_out;

  // ---------- workspace ----------
  char* pb = (char*)d_ws;
  auto allocH = [&](size_t nh) { _Float16* p = (_Float16*)pb; pb += nh * 2; return p; };
  _Float16* L0 = allocH((size_t)N_ALL * D);
  // layer-1 outputs in GLOBAL row space: us 60000 rows (identity),
  // uv 90000 rows (hole at [50000,60000)), sv 40000 rows (global - 50000)
  _Float16* Th0 = allocH((size_t)N_US * D);
  _Float16* Th1 = allocH((size_t)N_ALL * D);
  _Float16* Th2 = allocH((size_t)N_SV * D);
  _Float16* Ac[3] = {allocH((size_t)N_US * D), allocH((size_t)N_UV * D), allocH((size_t)N_SV * D)};
  _Float16* UVsH = allocH((size_t)NSc * D);
  _Float16* SVuH = allocH((size_t)NUc * D);
  pb = (char*)(((uintptr_t)pb + 15) & ~(uintptr_t)15);
  float* Pu = (float*)pb; pb += (size_t)Bc * D * 4;
  float* Ps = (float*)pb; pb += (size_t)Bc * D * 4;
  float* accs = (float*)pb; pb += 16 * 4;
  float* Su = (float*)pb; pb += Bc * 4;
  float* Ss = (float*)pb; pb += Bc * 4;
  int totE = nnz[0] + nnz[1] + nnz[2] + nnz[3] + nnz[4];
  int2* cvAll = (int2*)pb; pb += (size_t)totE * 8;
  int2* ibAll = (int2*)pb; pb += (size_t)totE * 8;
  int* rpAll = (int*)pb;
  int totRP = 0;
  for (int g = 0; g < 5; ++g) totRP += gn[g] + 1;
  pb += (size_t)totRP * 4;
  int* auxAll = (int*)pb; pb += 5 * 128 * 4;

  // ---------- CSR build descriptor ----------
  Bld b;
  int totCBlk = 0;
  {
    int eA = 0, sA = 0, rpO = 0, cvO = 0, bA = 0, cA = 0;
    // col remap local -> L0 global: c += (c>=thr ? add : 0)
    int thrC[5] = {0x7fffffff, NUc, 0, 0x7fffffff, 0x7fffffff};
    int addC[5] = {0, NSc, NUc, 0, 0};
    for (int g = 0; g < 5; ++g) {
      b.rows[g] = grows[g]; b.cols[g] = gcols[g]; b.vals[g] = gvals[g];
      b.thrC[g] = thrC[g]; b.addC[g] = addC[g];
      b.eBase[g] = eA; eA += nnz[g];
      int n1 = gn[g] + 1;
      b.nPlus1[g] = n1;
      b.sBlkBase[g] = sA; sA += (n1 + 1023) / 1024;
      b.cBlkBase[g] = cA; cA += (nnz[g] + CHUNK - 1) / CHUNK;
      b.rp[g] = rpAll + rpO; rpO += n1;
      b.aux[g] = auxAll + g * 128;
      b.cv[g] = cvAll + cvO;
      b.ibuf[g] = ibAll + cvO; cvO += nnz[g];
      b.bktBase[g] = bA; bA += (gn[g] + BW - 1) / BW;
    }
    b.eBase[5] = eA;
    b.sBlkBase[5] = sA;
    b.cBlkBase[5] = cA;
    b.bktBase[5] = bA;
    totCBlk = cA;
  }
  int totBlk = b.sBlkBase[5];
  int totBkt = b.bktBase[5];
  int* bhistAll = (int*)pb; pb += (size_t)totCBlk * NBH * 4;
  b.bhist = bhistAll;

  // ---------- keys (JAX threefry, partitionable fold-in split) ----------
  uint32_t kus[2], kuv[2], ksv[2], kauv[2], kasv[2];
  threefry(0u, 42u, 0u, 0u, kus[0], kus[1]);
  threefry(0u, 42u, 0u, 1u, kuv[0], kuv[1]);
  threefry(0u, 42u, 0u, 2u, ksv[0], ksv[1]);
  threefry(0u, 42u, 0u, 3u, kauv[0], kauv[1]);
  threefry(0u, 42u, 0u, 4u, kasv[0], kasv[1]);
  uint32_t kusL[2][2], kuvL[2][2], ksvL[2][2];
  for (uint32_t i = 0; i < 2; ++i) {
    threefry(kus[0], kus[1], 0u, i, kusL[i][0], kusL[i][1]);
    threefry(kuv[0], kuv[1], 0u, i, kuvL[i][0], kuvL[i][1]);
    threefry(ksv[0], ksv[1], 0u, i, ksvL[i][0], ksvL[i][1]);
  }

  // ---------- CSR build (deterministic two-level scatter) + L0 table ----------
  hipMemsetAsync(rpAll, 0, (size_t)totRP * sizeof(int), stream);
  int l0Blocks = (N_ALL * (D / 4) + 255) / 256;
  k_histl0<<<(unsigned)(totCBlk + l0Blocks), 256, 0, stream>>>(b, usersF, streamersF, videosF,
                                                               L0, totCBlk);
  k_scan1f<<<(unsigned)totBlk, 1024, 0, stream>>>(b);
  k_scan2f<<<5, 64, 0, stream>>>(b);
  k_scan3f<<<(unsigned)totBlk, 1024, 0, stream>>>(b);
  k_bscan<<<(unsigned)(((size_t)totBkt * 64 + 255) / 256), 256, 0, stream>>>(b);
  k_bscat<<<(unsigned)totCBlk, 256, 0, stream>>>(b);
  k_scatl2<<<(unsigned)totBkt, 256, 0, stream>>>(b);

  // ---------- propagate layers (fused over us/uv/sv) ----------
  GP p1, p2;
  const uint32_t* kL1[3] = {kusL[0], kuvL[0], ksvL[0]};
  const uint32_t* kL2[3] = {kusL[1], kuvL[1], ksvL[1]};
  int rB[4] = {0, N_US, N_US + N_UV, N_US + N_UV + N_SV};
  // per-graph row remap rl -> global row gr
  int rThr[3] = {0x7fffffff, NUc, 0};
  int rAdd[3] = {0, NSc, NUc};
  // dst pointers pre-offset so dst[gr] is correct
  _Float16* dstP[3] = {Th0, Th1, Th2 - (size_t)NUc * D};
  // layer-2 gather sources pre-offset so src[(gcol<<8)] is correct
  const char* src2[3] = {(const char*)Th0, (const char*)Th1,
                         (const char*)Th2 - (size_t)NUc * D * 2};
  for (int g = 0; g < 3; ++g) {
    p1.rp[g] = b.rp[g]; p1.cv[g] = b.cv[g];
    p1.src[g] = (const char*)L0; p1.accIn[g] = L0; p1.accOut[g] = Ac[g]; p1.dst[g] = dstP[g];
    p1.k0[g] = kL1[g][0]; p1.k1[g] = kL1[g][1];
    p1.rowThr[g] = rThr[g]; p1.rowAdd[g] = rAdd[g];
    p1.rBase[g] = rB[g];
    p2.rp[g] = b.rp[g]; p2.cv[g] = b.cv[g];
    p2.src[g] = src2[g]; p2.accIn[g] = Ac[g]; p2.accOut[g] = Ac[g]; p2.dst[g] = nullptr;
    p2.k0[g] = kL2[g][0]; p2.k1[g] = kL2[g][1];
    p2.rowThr[g] = 0x7fffffff; p2.rowAdd[g] = 0;
    p2.rBase[g] = rB[g];
  }
  p1.rBase[3] = rB[3]; p2.rBase[3] = rB[3];
  p1.div = 1.0f; p2.div = 3.0f;
  unsigned gpropBlocks = (unsigned)(((size_t)rB[3] * 64 + 255) / 256);
  k_gprop3<<<gpropBlocks, 256, 0, stream>>>(p1);
  k_gprop3<<<gpropBlocks, 256, 0, stream>>>(p2);

  // ---------- aggregates (fused) ----------
  GA ga;
  ga.rp[0] = b.rp[3]; ga.cv[0] = b.cv[3];
  ga.src[0] = (const char*)(Ac[2] + (size_t)NSc * D);  // SV video part (cols 0..NV)
  ga.dst[0] = SVuH; ga.k0[0] = kauv[0]; ga.k1[0] = kauv[1];
  ga.rp[1] = b.rp[4]; ga.cv[1] = b.cv[4];
  ga.src[1] = (const char*)(Ac[1] + (size_t)NUc * D);  // UV video part
  ga.dst[1] = UVsH; ga.k0[1] = kasv[0]; ga.k1[1] = kasv[1];
  ga.rBase[0] = 0; ga.rBase[1] = NUc; ga.rBase[2] = NUc + NSc;
  k_gagg2<<<(unsigned)(((size_t)(NUc + NSc) * 64 + 255) / 256), 256, 0, stream>>>(ga);

  // ---------- attention + losses ----------
  k_mga<<<(unsigned)((NUc + NSc + 3) / 4), 256, 0, stream>>>(Ac[0], Ac[1], UVsH, SVuH, Ac[2],
                                                             linW, linB);
  hipMemsetAsync(accs, 0, (size_t)(16 + 2 * Bc) * sizeof(float), stream);
  k_batch<<<(unsigned)((Bc + 3) / 4), 256, 0, stream>>>(Ac[0], users, streamers, Pu, Ps, accs);
  k_cgemm<<<dim3(Bc / 32, 4, 2), 256, 0, stream>>>(Pu, Ps, Su, Ss);
  k_cfinal<<<(unsigned)((2 * Bc + 3) / 4), 256, 0, stream>>>(Pu, Ps, Su, Ss, accs);
  k_final<<<1, 64, 0, stream>>>(accs, out);
}